// Round 2
// baseline (814.435 us; speedup 1.0000x reference)
//
#include <hip/hip_runtime.h>
#include <math.h>

#define TT 9
#define HH 128
#define WW 128
#define BB 8
#define SLICE (HH*WW)           // 16384
#define CHW (TT*SLICE)          // 147456
#define BCH (2*CHW)             // 294912
#define TOT (BB*BCH)            // 2359296
#define INV_M (1.0f/147456.0f)

// ---------------- K0: batch start offsets via binary search (b sorted) -----
__global__ void k_bounds(const int* __restrict__ b, int* __restrict__ start, int n) {
    int tid = threadIdx.x;
    if (tid > 8) return;
    if (tid == 0) { start[0] = 0; return; }
    if (tid == 8) { start[8] = n; return; }
    int lo = 0, hi = n;
    while (lo < hi) { int mid = (lo + hi) >> 1; if (b[mid] < tid) lo = mid + 1; else hi = mid; }
    start[tid] = lo;
}

// ---------------- K1: per-batch max of t (batch<->XCD affinity) ------------
__global__ void k_tmax(const float* __restrict__ t, const int* __restrict__ start,
                       unsigned* __restrict__ gmax) {
    __shared__ unsigned sm[256];
    int bi = blockIdx.x & 7;
    int cj = blockIdx.x >> 3;
    int nb = gridDim.x >> 3;
    int s = start[bi], e = start[bi + 1];
    int len = e - s;
    if (len <= 0) return;
    int per = (len + nb - 1) / nb;
    int lo = s + cj * per;
    int hi = lo + per < e ? lo + per : e;
    unsigned m = 0u;
    for (int i = lo + threadIdx.x; i < hi; i += 256) {
        unsigned tv = __float_as_uint(t[i]);   // t >= 0: uint order == float order
        if (tv > m) m = tv;
    }
    sm[threadIdx.x] = m;
    __syncthreads();
    for (int ofs = 128; ofs > 0; ofs >>= 1) {
        if (threadIdx.x < ofs && sm[threadIdx.x + ofs] > sm[threadIdx.x])
            sm[threadIdx.x] = sm[threadIdx.x + ofs];
        __syncthreads();
    }
    if (threadIdx.x == 0 && sm[0]) atomicMax(&gmax[bi], sm[0]);
}

// ---------------- K2: voxelize scatter, batch<->XCD affinity ---------------
// All atomics of batch bi come from blocks with blockIdx%8==bi, which land on
// one XCD; the batch's 1.18 MB vox region stays resident in that XCD's L2.
__global__ void __launch_bounds__(256) k_vox(
        const float* __restrict__ t, const int* __restrict__ x,
        const int* __restrict__ y, const int* __restrict__ p,
        const unsigned* __restrict__ gmax, const int* __restrict__ start,
        float* __restrict__ vox) {
    int bi = blockIdx.x & 7;
    int cj = blockIdx.x >> 3;
    int nb = gridDim.x >> 3;
    int s = start[bi], e = start[bi + 1];
    int len = e - s;
    if (len <= 0) return;
    int per = (len + nb - 1) / nb;
    int lo = s + cj * per;
    int hi = lo + per < e ? lo + per : e;
    float tmax = __uint_as_float(gmax[bi]);
    float* vb = vox + (long)bi * BCH;
    for (int i = lo + threadIdx.x; i < hi; i += 256) {
        float ts = t[i] / tmax * 9.0f;          // same op order as reference
        int base = x[i] + WW * y[i] + CHW * p[i];
        float fl = floorf(ts);
        int i0 = (int)fl;                        // t>=0 -> i0>=0
        if (i0 < TT)
            atomicAdd(&vb[base + SLICE * i0], 1.0f - (ts - fl));
        int i1 = i0 + 1;
        if (i1 < TT)
            atomicAdd(&vb[base + SLICE * i1], 1.0f - ((float)i1 - ts));
    }
}

// ---------------- K3: per-(b,c) sum / sumsq of vox -------------------------
__global__ void k_stats1(const float* __restrict__ vox, float* __restrict__ s1) {
    __shared__ float ss[256], sq[256];
    int bc = blockIdx.x >> 5, part = blockIdx.x & 31;
    const float4* vp = (const float4*)(vox + (long)bc * CHW);
    const int per = (CHW / 4) / 32;   // 1152 float4 per part
    float s = 0.f, q = 0.f;
    for (int j = part * per + threadIdx.x; j < (part + 1) * per; j += 256) {
        float4 v = vp[j];
        s += v.x + v.y + v.z + v.w;
        q += v.x * v.x + v.y * v.y + v.z * v.z + v.w * v.w;
    }
    ss[threadIdx.x] = s; sq[threadIdx.x] = q;
    __syncthreads();
    for (int ofs = 128; ofs > 0; ofs >>= 1) {
        if (threadIdx.x < ofs) { ss[threadIdx.x] += ss[threadIdx.x + ofs]; sq[threadIdx.x] += sq[threadIdx.x + ofs]; }
        __syncthreads();
    }
    if (threadIdx.x == 0) { atomicAdd(&s1[bc], ss[0]); atomicAdd(&s1[16 + bc], sq[0]); }
}

// ---------------- K4: time-corr mask (one block per (b,c,t) slice) ---------
__global__ void k_mask(const float* __restrict__ vox, float* __restrict__ mask) {
    __shared__ unsigned char sbx[SLICE];
    __shared__ unsigned char sar[SLICE];
    int bid = blockIdx.x;                 // 144 = 8*2*9
    int t = bid % 9, c = (bid / 9) & 1, bb = bid / 18;
    long off = (long)bb * BCH + (long)c * CHW;
    const float* vt = vox + off + (long)t * SLICE;
    int tn = (t + 1 < 9) ? t + 1 : 8;     // replication pad in T
    const float* vn = vox + off + (long)tn * SLICE;
    for (int i = threadIdx.x; i < SLICE; i += 256)
        sbx[i] = (vt[i] > 0.0f) ? 1 : 0;
    __syncthreads();
    for (int i = threadIdx.x; i < SLICE; i += 256) {
        int yy = i >> 7, xx = i & 127;
        int s = 0;
        for (int dy = -1; dy <= 1; ++dy) {
            int y2 = yy + dy; if ((unsigned)y2 >= 128u) continue;
            for (int dx = -1; dx <= 1; ++dx) {
                int x2 = xx + dx; if ((unsigned)x2 >= 128u) continue;
                s += sbx[(y2 << 7) + x2];
            }
        }
        // prev*bxn > 4/9  <=>  bxn==1 && boxsum >= 5   (exact, s is an integer)
        sar[i] = (vn[i] > 0.0f && s >= 5) ? 1 : 0;
    }
    __syncthreads();
    float* mt = mask + off + (long)t * SLICE;
    for (int i = threadIdx.x; i < SLICE; i += 256) {
        int yy = i >> 7, xx = i & 127;
        int s = 0;
        for (int dy = -1; dy <= 1; ++dy) {
            int y2 = yy + dy; if ((unsigned)y2 >= 128u) continue;
            for (int dx = -1; dx <= 1; ++dx) {
                int x2 = xx + dx; if ((unsigned)x2 >= 128u) continue;
                s += sar[(y2 << 7) + x2];
            }
        }
        mt[i] = (float)s / 9.0f;
    }
}

// ---------------- K5: fold stats + collapse conv1/dyn/conv3 to K[2][2][3] --
__global__ void k_prep(const float* __restrict__ conv1_w, const float* __restrict__ dyn_w,
                       const float* __restrict__ conv3_w, const float* __restrict__ s1,
                       float* __restrict__ nrm, float* __restrict__ Kc) {
    int tid = threadIdx.x;
    if (tid < 16) {
        float m = s1[tid] * INV_M;
        float var = s1[16 + tid] * INV_M - m * m;
        float inv = rsqrtf(var + 1e-5f);
        nrm[tid] = inv;           // scale
        nrm[16 + tid] = -m * inv; // shift
    }
    if (tid < 12) {
        int d = tid % 3, c = (tid / 3) & 1, o2 = tid / 6;
        float acc = 0.0f;
        for (int o = 0; o < 16; ++o) {
            float c3 = conv3_w[o2 * 16 + o];
            for (int i = 0; i < 16; ++i) {
                float wsum = 0.0f;
                for (int k = 0; k < 4; ++k) wsum += dyn_w[((k * 16 + o) * 16 + i) * 3 + d];
                acc += c3 * (0.25f * wsum) * conv1_w[i * 2 + c];
                // attention is exactly uniform: pooled mean of inorm output is 0
            }
        }
        Kc[tid] = acc;            // Kc[o2*6 + c*3 + d]
    }
}

// ---------------- K6: pre-act conv + sigmoid*mask + stats2 -----------------
__global__ void k_g(const float* __restrict__ vox, float* __restrict__ gm,
                    const float* __restrict__ nrm, const float* __restrict__ Kc,
                    float* __restrict__ s2) {
    int i = blockIdx.x * 256 + threadIdx.x;     // grid covers TOT exactly
    int bb = i / BCH;
    int o2 = (i / CHW) & 1;
    int t = (i / SLICE) % 9;
    int hw = i & (SLICE - 1);
    const float* Kk = Kc + o2 * 6;
    float pre = 0.0f;
    for (int c = 0; c < 2; ++c) {
        float sc = nrm[bb * 2 + c], sh = nrm[16 + bb * 2 + c];
        const float* vbase = vox + (long)bb * BCH + (long)c * CHW + hw;
        for (int d = 0; d < 3; ++d) {
            int tau = t - 1 + d;
            if ((unsigned)tau < 9u) {
                float nv = vbase[(long)tau * SLICE] * sc + sh;
                pre += Kk[c * 3 + d] * nv;
            }
        }
    }
    float sig = 1.0f / (1.0f + expf(-pre));
    float g = sig * gm[i];                      // gm holds mask, becomes g
    gm[i] = g;
    __shared__ float ss[256], sq[256];
    ss[threadIdx.x] = g; sq[threadIdx.x] = g * g;
    __syncthreads();
    for (int ofs = 128; ofs > 0; ofs >>= 1) {
        if (threadIdx.x < ofs) { ss[threadIdx.x] += ss[threadIdx.x + ofs]; sq[threadIdx.x] += sq[threadIdx.x + ofs]; }
        __syncthreads();
    }
    if (threadIdx.x == 0) {
        int bc = bb * 2 + o2;
        atomicAdd(&s2[bc], ss[0]); atomicAdd(&s2[16 + bc], sq[0]);
    }
}

// ---------------- K7: final instance norm in place -------------------------
__global__ void k_norm(float* __restrict__ out, const float* __restrict__ s2) {
    int i = blockIdx.x * 256 + threadIdx.x;
    int bc = i / CHW;
    float m = s2[bc] * INV_M;
    float var = s2[16 + bc] * INV_M - m * m;
    float inv = rsqrtf(var + 1e-5f);
    out[i] = (out[i] - m) * inv;
}

extern "C" void kernel_launch(void* const* d_in, const int* in_sizes, int n_in,
                              void* d_out, int out_size, void* d_ws, size_t ws_size,
                              hipStream_t stream) {
    const float* t  = (const float*)d_in[0];
    const int*   x  = (const int*)d_in[1];
    const int*   y  = (const int*)d_in[2];
    const int*   p  = (const int*)d_in[3];
    const int*   b  = (const int*)d_in[4];
    const float* conv1_w = (const float*)d_in[5];
    // d_in[6], d_in[7] (fc1_w, fc2_w): unused — attention is exactly uniform
    const float* dyn_w   = (const float*)d_in[8];
    const float* conv3_w = (const float*)d_in[9];
    float* out = (float*)d_out;
    int n = in_sizes[0];

    float*    ws    = (float*)d_ws;
    float*    vox   = ws;                        // TOT floats
    unsigned* gmax  = (unsigned*)(ws + TOT);     // 8
    float*    s1    = ws + TOT + 8;              // 32
    float*    nrm   = ws + TOT + 40;             // 32
    float*    Kc    = ws + TOT + 72;             // 12
    float*    s2    = ws + TOT + 84;             // 32
    int*      start = (int*)(ws + TOT + 116);    // 9

    hipMemsetAsync(d_ws, 0, (size_t)(TOT + 128) * sizeof(float), stream);

    k_bounds<<<1, 64, 0, stream>>>(b, start, n);
    k_tmax<<<2048, 256, 0, stream>>>(t, start, gmax);
    k_vox<<<2048, 256, 0, stream>>>(t, x, y, p, gmax, start, vox);
    k_stats1<<<512, 256, 0, stream>>>(vox, s1);
    k_mask<<<144, 256, 0, stream>>>(vox, out);   // d_out holds mask temporarily
    k_prep<<<1, 64, 0, stream>>>(conv1_w, dyn_w, conv3_w, s1, nrm, Kc);
    k_g<<<TOT / 256, 256, 0, stream>>>(vox, out, nrm, Kc, s2);
    k_norm<<<TOT / 256, 256, 0, stream>>>(out, s2);
}

// Round 3
// 678.997 us; speedup vs baseline: 1.1995x; 1.1995x over previous
//
#include <hip/hip_runtime.h>
#include <math.h>

#define TT 9
#define HH 128
#define WW 128
#define BB 8
#define SLICE (HH*WW)           // 16384
#define CHW (TT*SLICE)          // 147456
#define BCH (2*CHW)             // 294912
#define TOT (BB*BCH)            // 2359296
#define INV_M (1.0f/147456.0f)

// ---------------- K0: batch start offsets via binary search (b sorted) -----
__global__ void k_bounds(const int* __restrict__ b, int* __restrict__ start, int n) {
    int tid = threadIdx.x;
    if (tid > 8) return;
    if (tid == 0) { start[0] = 0; return; }
    if (tid == 8) { start[8] = n; return; }
    int lo = 0, hi = n;
    while (lo < hi) { int mid = (lo + hi) >> 1; if (b[mid] < tid) lo = mid + 1; else hi = mid; }
    start[tid] = lo;
}

// ---------------- K1: per-batch max of t -----------------------------------
__global__ void k_tmax(const float* __restrict__ t, const int* __restrict__ start,
                       unsigned* __restrict__ gmax) {
    __shared__ unsigned sm[256];
    int bi = blockIdx.x & 7;
    int cj = blockIdx.x >> 3;
    int nb = gridDim.x >> 3;
    int s = start[bi], e = start[bi + 1];
    int len = e - s;
    if (len <= 0) return;
    int per = (len + nb - 1) / nb;
    int lo = s + cj * per;
    int hi = lo + per < e ? lo + per : e;
    unsigned m = 0u;
    for (int i = lo + threadIdx.x; i < hi; i += 256) {
        unsigned tv = __float_as_uint(t[i]);   // t >= 0: uint order == float order
        if (tv > m) m = tv;
    }
    sm[threadIdx.x] = m;
    __syncthreads();
    for (int ofs = 128; ofs > 0; ofs >>= 1) {
        if (threadIdx.x < ofs && sm[threadIdx.x + ofs] > sm[threadIdx.x])
            sm[threadIdx.x] = sm[threadIdx.x + ofs];
        __syncthreads();
    }
    if (threadIdx.x == 0 && sm[0]) atomicMax(&gmax[bi], sm[0]);
}

// ---------------- K2: scatter via per-(b,t) LDS slice ownership ------------
// Block (tg, b, e): owns the dense [2][128][128] region (both polarities) of
// time-bin tg for batch b, accumulated in 128 KB LDS; scans event chunk e and
// accepts only deposits targeting bin tg (~2/9). NO global atomics at all.
__global__ void __launch_bounds__(512) k_scat(
        const float* __restrict__ t, const int* __restrict__ x,
        const int* __restrict__ y, const int* __restrict__ p,
        const unsigned* __restrict__ gmax, const int* __restrict__ start,
        float* __restrict__ vox, float* __restrict__ part, int E) {
    __shared__ float sl[2 * SLICE];              // 128 KiB
    int tg = blockIdx.x;                         // 0..8 time bin
    int bb = blockIdx.y;                         // batch
    int e  = blockIdx.z;                         // event split
    int s = start[bb], en = start[bb + 1];
    long len = en - s;
    int cs = s + (int)(len * e / E);
    int ce = s + (int)(len * (e + 1) / E);
    for (int j = threadIdx.x; j < 2 * SLICE; j += 512) sl[j] = 0.0f;
    __syncthreads();
    float tmax = __uint_as_float(gmax[bb]);
    float ftg = (float)tg;
    for (int i = cs + threadIdx.x; i < ce; i += 512) {
        float ts = t[i] / tmax * 9.0f;           // same op order as reference
        float fl = floorf(ts);
        int i0 = (int)fl;
        if (i0 == tg || i0 + 1 == tg) {
            // i0==tg: w = 1-(ts-fl); i0+1==tg: w = 1-((float)(i0+1)-ts)  (bit-exact)
            float w = (i0 == tg) ? (1.0f - (ts - fl)) : (1.0f - (ftg - ts));
            int hw = x[i] + (y[i] << 7) + (p[i] << 14);
            atomicAdd(&sl[hw], w);               // LDS atomic, rare collisions
        }
    }
    __syncthreads();
    float* dst = (E > 1 ? part + (size_t)e * TOT : vox)
               + (size_t)bb * BCH + (size_t)tg * SLICE;
    for (int j = threadIdx.x; j < SLICE; j += 512) {
        dst[j]       = sl[j];                    // p=0 slice
        dst[CHW + j] = sl[SLICE + j];            // p=1 slice
    }
}

// ---------------- K2b: merge E partials + inorm stats (E>1 path) -----------
__global__ void k_merge(const float* __restrict__ part, float* __restrict__ vox,
                        float* __restrict__ s1, int E) {
    __shared__ float ss[256], sq[256];
    int i4 = blockIdx.x * 256 + threadIdx.x;     // float4 index; grid=TOT/1024
    const float4* pp = (const float4*)part;
    float4 a = pp[i4];
    for (int e = 1; e < E; ++e) {
        float4 v = pp[(size_t)e * (TOT / 4) + i4];
        a.x += v.x; a.y += v.y; a.z += v.z; a.w += v.w;
    }
    ((float4*)vox)[i4] = a;
    ss[threadIdx.x] = a.x + a.y + a.z + a.w;
    sq[threadIdx.x] = a.x * a.x + a.y * a.y + a.z * a.z + a.w * a.w;
    __syncthreads();
    for (int ofs = 128; ofs > 0; ofs >>= 1) {
        if (threadIdx.x < ofs) { ss[threadIdx.x] += ss[threadIdx.x + ofs]; sq[threadIdx.x] += sq[threadIdx.x + ofs]; }
        __syncthreads();
    }
    if (threadIdx.x == 0) {
        int bc = i4 / (CHW / 4);                 // block fully within one (b,c)
        atomicAdd(&s1[bc], ss[0]); atomicAdd(&s1[16 + bc], sq[0]);
    }
}

// ---------------- K3: per-(b,c) sum / sumsq of vox (E==1 path) -------------
__global__ void k_stats1(const float* __restrict__ vox, float* __restrict__ s1) {
    __shared__ float ss[256], sq[256];
    int bc = blockIdx.x >> 5, part = blockIdx.x & 31;
    const float4* vp = (const float4*)(vox + (long)bc * CHW);
    const int per = (CHW / 4) / 32;
    float s = 0.f, q = 0.f;
    for (int j = part * per + threadIdx.x; j < (part + 1) * per; j += 256) {
        float4 v = vp[j];
        s += v.x + v.y + v.z + v.w;
        q += v.x * v.x + v.y * v.y + v.z * v.z + v.w * v.w;
    }
    ss[threadIdx.x] = s; sq[threadIdx.x] = q;
    __syncthreads();
    for (int ofs = 128; ofs > 0; ofs >>= 1) {
        if (threadIdx.x < ofs) { ss[threadIdx.x] += ss[threadIdx.x + ofs]; sq[threadIdx.x] += sq[threadIdx.x + ofs]; }
        __syncthreads();
    }
    if (threadIdx.x == 0) { atomicAdd(&s1[bc], ss[0]); atomicAdd(&s1[16 + bc], sq[0]); }
}

// ---------------- K4: time-corr mask (one block per (b,c,t) slice) ---------
__global__ void k_mask(const float* __restrict__ vox, float* __restrict__ mask) {
    __shared__ unsigned char sbx[SLICE];
    __shared__ unsigned char sar[SLICE];
    int bid = blockIdx.x;                 // 144 = 8*2*9
    int t = bid % 9, c = (bid / 9) & 1, bb = bid / 18;
    long off = (long)bb * BCH + (long)c * CHW;
    const float* vt = vox + off + (long)t * SLICE;
    int tn = (t + 1 < 9) ? t + 1 : 8;     // replication pad in T
    const float* vn = vox + off + (long)tn * SLICE;
    for (int i = threadIdx.x; i < SLICE; i += 256)
        sbx[i] = (vt[i] > 0.0f) ? 1 : 0;
    __syncthreads();
    for (int i = threadIdx.x; i < SLICE; i += 256) {
        int yy = i >> 7, xx = i & 127;
        int s = 0;
        for (int dy = -1; dy <= 1; ++dy) {
            int y2 = yy + dy; if ((unsigned)y2 >= 128u) continue;
            for (int dx = -1; dx <= 1; ++dx) {
                int x2 = xx + dx; if ((unsigned)x2 >= 128u) continue;
                s += sbx[(y2 << 7) + x2];
            }
        }
        // prev*bxn > 4/9  <=>  bxn==1 && boxsum >= 5   (exact, s is an integer)
        sar[i] = (vn[i] > 0.0f && s >= 5) ? 1 : 0;
    }
    __syncthreads();
    float* mt = mask + off + (long)t * SLICE;
    for (int i = threadIdx.x; i < SLICE; i += 256) {
        int yy = i >> 7, xx = i & 127;
        int s = 0;
        for (int dy = -1; dy <= 1; ++dy) {
            int y2 = yy + dy; if ((unsigned)y2 >= 128u) continue;
            for (int dx = -1; dx <= 1; ++dx) {
                int x2 = xx + dx; if ((unsigned)x2 >= 128u) continue;
                s += sar[(y2 << 7) + x2];
            }
        }
        mt[i] = (float)s / 9.0f;
    }
}

// ---------------- K5: fold stats + collapse conv1/dyn/conv3 to K[2][2][3] --
__global__ void k_prep(const float* __restrict__ conv1_w, const float* __restrict__ dyn_w,
                       const float* __restrict__ conv3_w, const float* __restrict__ s1,
                       float* __restrict__ nrm, float* __restrict__ Kc) {
    int tid = threadIdx.x;
    if (tid < 16) {
        float m = s1[tid] * INV_M;
        float var = s1[16 + tid] * INV_M - m * m;
        float inv = rsqrtf(var + 1e-5f);
        nrm[tid] = inv;           // scale
        nrm[16 + tid] = -m * inv; // shift
    }
    if (tid < 12) {
        int d = tid % 3, c = (tid / 3) & 1, o2 = tid / 6;
        float acc = 0.0f;
        for (int o = 0; o < 16; ++o) {
            float c3 = conv3_w[o2 * 16 + o];
            for (int i = 0; i < 16; ++i) {
                float wsum = 0.0f;
                for (int k = 0; k < 4; ++k) wsum += dyn_w[((k * 16 + o) * 16 + i) * 3 + d];
                acc += c3 * (0.25f * wsum) * conv1_w[i * 2 + c];
                // attention is exactly uniform: pooled mean of inorm output is 0
            }
        }
        Kc[tid] = acc;            // Kc[o2*6 + c*3 + d]
    }
}

// ---------------- K6: pre-act conv + sigmoid*mask + stats2 -----------------
__global__ void k_g(const float* __restrict__ vox, float* __restrict__ gm,
                    const float* __restrict__ nrm, const float* __restrict__ Kc,
                    float* __restrict__ s2) {
    int i = blockIdx.x * 256 + threadIdx.x;     // grid covers TOT exactly
    int bb = i / BCH;
    int o2 = (i / CHW) & 1;
    int t = (i / SLICE) % 9;
    int hw = i & (SLICE - 1);
    const float* Kk = Kc + o2 * 6;
    float pre = 0.0f;
    for (int c = 0; c < 2; ++c) {
        float sc = nrm[bb * 2 + c], sh = nrm[16 + bb * 2 + c];
        const float* vbase = vox + (long)bb * BCH + (long)c * CHW + hw;
        for (int d = 0; d < 3; ++d) {
            int tau = t - 1 + d;
            if ((unsigned)tau < 9u) {
                float nv = vbase[(long)tau * SLICE] * sc + sh;
                pre += Kk[c * 3 + d] * nv;
            }
        }
    }
    float sig = 1.0f / (1.0f + expf(-pre));
    float g = sig * gm[i];                      // gm holds mask, becomes g
    gm[i] = g;
    __shared__ float ss[256], sq[256];
    ss[threadIdx.x] = g; sq[threadIdx.x] = g * g;
    __syncthreads();
    for (int ofs = 128; ofs > 0; ofs >>= 1) {
        if (threadIdx.x < ofs) { ss[threadIdx.x] += ss[threadIdx.x + ofs]; sq[threadIdx.x] += sq[threadIdx.x + ofs]; }
        __syncthreads();
    }
    if (threadIdx.x == 0) {
        int bc = bb * 2 + o2;
        atomicAdd(&s2[bc], ss[0]); atomicAdd(&s2[16 + bc], sq[0]);
    }
}

// ---------------- K7: final instance norm in place -------------------------
__global__ void k_norm(float* __restrict__ out, const float* __restrict__ s2) {
    int i = blockIdx.x * 256 + threadIdx.x;
    int bc = i / CHW;
    float m = s2[bc] * INV_M;
    float var = s2[16 + bc] * INV_M - m * m;
    float inv = rsqrtf(var + 1e-5f);
    out[i] = (out[i] - m) * inv;
}

extern "C" void kernel_launch(void* const* d_in, const int* in_sizes, int n_in,
                              void* d_out, int out_size, void* d_ws, size_t ws_size,
                              hipStream_t stream) {
    const float* t  = (const float*)d_in[0];
    const int*   x  = (const int*)d_in[1];
    const int*   y  = (const int*)d_in[2];
    const int*   p  = (const int*)d_in[3];
    const int*   b  = (const int*)d_in[4];
    const float* conv1_w = (const float*)d_in[5];
    // d_in[6], d_in[7] (fc1_w, fc2_w): unused — attention is exactly uniform
    const float* dyn_w   = (const float*)d_in[8];
    const float* conv3_w = (const float*)d_in[9];
    float* out = (float*)d_out;
    int n = in_sizes[0];

    // event-split factor from available workspace (deterministic per ws_size)
    size_t availF = ws_size / sizeof(float);
    int E = 1;
    if (availF >= (size_t)(2L * TOT + 128)) {
        long e = (long)((availF - TOT - 128) / TOT);
        E = e > 7 ? 7 : (int)e;
        if (E < 1) E = 1;
    }

    float*    ws    = (float*)d_ws;
    float*    vox   = ws;                                    // TOT floats
    float*    part  = ws + TOT;                              // E*TOT (E>1)
    float*    tail  = ws + TOT + (E > 1 ? (size_t)E * TOT : 0);
    unsigned* gmax  = (unsigned*)tail;                       // 8
    float*    s1    = tail + 8;                              // 32
    float*    nrm   = tail + 40;                             // 32
    float*    Kc    = tail + 72;                             // 12
    float*    s2    = tail + 84;                             // 32
    int*      start = (int*)(tail + 116);                    // 9

    hipMemsetAsync(tail, 0, 128 * sizeof(float), stream);    // only the small stats

    k_bounds<<<1, 64, 0, stream>>>(b, start, n);
    k_tmax<<<2048, 256, 0, stream>>>(t, start, gmax);
    k_scat<<<dim3(9, 8, E), 512, 0, stream>>>(t, x, y, p, gmax, start, vox, part, E);
    if (E > 1) k_merge<<<TOT / 1024, 256, 0, stream>>>(part, vox, s1, E);
    else       k_stats1<<<512, 256, 0, stream>>>(vox, s1);
    k_mask<<<144, 256, 0, stream>>>(vox, out);               // d_out holds mask
    k_prep<<<1, 64, 0, stream>>>(conv1_w, dyn_w, conv3_w, s1, nrm, Kc);
    k_g<<<TOT / 256, 256, 0, stream>>>(vox, out, nrm, Kc, s2);
    k_norm<<<TOT / 256, 256, 0, stream>>>(out, s2);
}

// Round 4
// 401.054 us; speedup vs baseline: 2.0307x; 1.6930x over previous
//
#include <hip/hip_runtime.h>
#include <math.h>

#define TT 9
#define HH 128
#define WW 128
#define BB 8
#define SLICE (HH*WW)           // 16384
#define CHW (TT*SLICE)          // 147456
#define BCH (2*CHW)             // 294912
#define TOT (BB*BCH)            // 2359296
#define INV_M (1.0f/147456.0f)

// ---------------- K0: batch start offsets via binary search (b sorted) -----
__global__ void k_bounds(const int* __restrict__ b, int* __restrict__ start, int n) {
    int tid = threadIdx.x;
    if (tid > 8) return;
    if (tid == 0) { start[0] = 0; return; }
    if (tid == 8) { start[8] = n; return; }
    int lo = 0, hi = n;
    while (lo < hi) { int mid = (lo + hi) >> 1; if (b[mid] < tid) lo = mid + 1; else hi = mid; }
    start[tid] = lo;
}

// ---------------- K1: per-batch max of t -----------------------------------
__global__ void k_tmax(const float* __restrict__ t, const int* __restrict__ start,
                       unsigned* __restrict__ gmax) {
    __shared__ unsigned sm[256];
    int bi = blockIdx.x & 7;
    int cj = blockIdx.x >> 3;
    int nb = gridDim.x >> 3;
    int s = start[bi], e = start[bi + 1];
    int len = e - s;
    if (len <= 0) return;
    int per = (len + nb - 1) / nb;
    int lo = s + cj * per;
    int hi = lo + per < e ? lo + per : e;
    unsigned m = 0u;
    for (int i = lo + threadIdx.x; i < hi; i += 256) {
        unsigned tv = __float_as_uint(t[i]);   // t >= 0: uint order == float order
        if (tv > m) m = tv;
    }
    sm[threadIdx.x] = m;
    __syncthreads();
    for (int ofs = 128; ofs > 0; ofs >>= 1) {
        if (threadIdx.x < ofs && sm[threadIdx.x + ofs] > sm[threadIdx.x])
            sm[threadIdx.x] = sm[threadIdx.x + ofs];
        __syncthreads();
    }
    if (threadIdx.x == 0 && sm[0]) atomicMax(&gmax[bi], sm[0]);
}

// ---------------- K1b: pack events to 8B records (ts bits, hw|p key) -------
__global__ void k_pack(const float* __restrict__ t, const int* __restrict__ x,
                       const int* __restrict__ y, const int* __restrict__ p,
                       const unsigned* __restrict__ gmax, const int* __restrict__ start,
                       int2* __restrict__ rec) {
    int bi = blockIdx.x & 7;
    int cj = blockIdx.x >> 3;
    int nb = gridDim.x >> 3;
    int s = start[bi], e = start[bi + 1];
    int len = e - s;
    if (len <= 0) return;
    int per = (len + nb - 1) / nb;
    int lo = s + cj * per;
    int hi = lo + per < e ? lo + per : e;
    float tmax = __uint_as_float(gmax[bi]);
    for (int i = lo + threadIdx.x; i < hi; i += 256) {
        float ts = t[i] / tmax * 9.0f;           // same op order as reference
        int key = x[i] + (y[i] << 7) + (p[i] << 14);
        rec[i] = make_int2(__float_as_int(ts), key);
    }
}

// ---------------- K2: scatter via per-(b,t) LDS slice ownership (packed) ---
__global__ void __launch_bounds__(512) k_scat_p(
        const int2* __restrict__ rec, const int* __restrict__ start,
        float* __restrict__ vox, float* __restrict__ part, int E) {
    __shared__ float sl[2 * SLICE];              // 128 KiB
    int tg = blockIdx.x, bb = blockIdx.y, e = blockIdx.z;
    int s = start[bb], en = start[bb + 1];
    long len = en - s;
    int cs = s + (int)(len * e / E);
    int ce = s + (int)(len * (e + 1) / E);
    for (int j = threadIdx.x; j < 2 * SLICE; j += 512) sl[j] = 0.0f;
    __syncthreads();
    float ftg = (float)tg;
    for (int i = cs + threadIdx.x; i < ce; i += 512) {
        int2 r = rec[i];
        float ts = __int_as_float(r.x);
        float fl = floorf(ts);
        int i0 = (int)fl;
        bool h0 = (i0 == tg), h1 = (i0 + 1 == tg);
        if (h0 | h1) {
            float w = h0 ? (1.0f - (ts - fl)) : (1.0f - (ftg - ts));  // bit-exact vs ref
            atomicAdd(&sl[r.y], w);
        }
    }
    __syncthreads();
    float* dst = (E > 1 ? part + (size_t)e * TOT : vox)
               + (size_t)bb * BCH + (size_t)tg * SLICE;
    for (int j = threadIdx.x; j < SLICE; j += 512) {
        dst[j]       = sl[j];
        dst[CHW + j] = sl[SLICE + j];
    }
}

// ---------------- K2 fallback: unpacked event scan -------------------------
__global__ void __launch_bounds__(512) k_scat(
        const float* __restrict__ t, const int* __restrict__ x,
        const int* __restrict__ y, const int* __restrict__ p,
        const unsigned* __restrict__ gmax, const int* __restrict__ start,
        float* __restrict__ vox, float* __restrict__ part, int E) {
    __shared__ float sl[2 * SLICE];
    int tg = blockIdx.x, bb = blockIdx.y, e = blockIdx.z;
    int s = start[bb], en = start[bb + 1];
    long len = en - s;
    int cs = s + (int)(len * e / E);
    int ce = s + (int)(len * (e + 1) / E);
    for (int j = threadIdx.x; j < 2 * SLICE; j += 512) sl[j] = 0.0f;
    __syncthreads();
    float tmax = __uint_as_float(gmax[bb]);
    float ftg = (float)tg;
    for (int i = cs + threadIdx.x; i < ce; i += 512) {
        float ts = t[i] / tmax * 9.0f;
        float fl = floorf(ts);
        int i0 = (int)fl;
        bool h0 = (i0 == tg), h1 = (i0 + 1 == tg);
        if (h0 | h1) {
            float w = h0 ? (1.0f - (ts - fl)) : (1.0f - (ftg - ts));
            int hw = x[i] + (y[i] << 7) + (p[i] << 14);
            atomicAdd(&sl[hw], w);
        }
    }
    __syncthreads();
    float* dst = (E > 1 ? part + (size_t)e * TOT : vox)
               + (size_t)bb * BCH + (size_t)tg * SLICE;
    for (int j = threadIdx.x; j < SLICE; j += 512) {
        dst[j]       = sl[j];
        dst[CHW + j] = sl[SLICE + j];
    }
}

// ---------------- K2b: merge E partials + inorm stats (E>1 path) -----------
__global__ void k_merge(const float* __restrict__ part, float* __restrict__ vox,
                        float* __restrict__ s1, int E) {
    __shared__ float ss[256], sq[256];
    int i4 = blockIdx.x * 256 + threadIdx.x;     // float4 index; grid=TOT/1024
    const float4* pp = (const float4*)part;
    float4 a = pp[i4];
    for (int e = 1; e < E; ++e) {
        float4 v = pp[(size_t)e * (TOT / 4) + i4];
        a.x += v.x; a.y += v.y; a.z += v.z; a.w += v.w;
    }
    ((float4*)vox)[i4] = a;
    ss[threadIdx.x] = a.x + a.y + a.z + a.w;
    sq[threadIdx.x] = a.x * a.x + a.y * a.y + a.z * a.z + a.w * a.w;
    __syncthreads();
    for (int ofs = 128; ofs > 0; ofs >>= 1) {
        if (threadIdx.x < ofs) { ss[threadIdx.x] += ss[threadIdx.x + ofs]; sq[threadIdx.x] += sq[threadIdx.x + ofs]; }
        __syncthreads();
    }
    if (threadIdx.x == 0) {
        int bc = i4 / (CHW / 4);
        atomicAdd(&s1[bc], ss[0]); atomicAdd(&s1[16 + bc], sq[0]);
    }
}

// ---------------- K3: per-(b,c) sum / sumsq of vox (E==1 path) -------------
__global__ void k_stats1(const float* __restrict__ vox, float* __restrict__ s1) {
    __shared__ float ss[256], sq[256];
    int bc = blockIdx.x >> 5, part = blockIdx.x & 31;
    const float4* vp = (const float4*)(vox + (long)bc * CHW);
    const int per = (CHW / 4) / 32;
    float s = 0.f, q = 0.f;
    for (int j = part * per + threadIdx.x; j < (part + 1) * per; j += 256) {
        float4 v = vp[j];
        s += v.x + v.y + v.z + v.w;
        q += v.x * v.x + v.y * v.y + v.z * v.z + v.w * v.w;
    }
    ss[threadIdx.x] = s; sq[threadIdx.x] = q;
    __syncthreads();
    for (int ofs = 128; ofs > 0; ofs >>= 1) {
        if (threadIdx.x < ofs) { ss[threadIdx.x] += ss[threadIdx.x + ofs]; sq[threadIdx.x] += sq[threadIdx.x + ofs]; }
        __syncthreads();
    }
    if (threadIdx.x == 0) { atomicAdd(&s1[bc], ss[0]); atomicAdd(&s1[16 + bc], sq[0]); }
}

// ---------------- K4: time-corr mask, y-strip parallel (576 blocks) --------
#define STRIP 32
__global__ void k_mask(const float* __restrict__ vox, float* __restrict__ mask) {
    __shared__ unsigned char sbx[36 * 128];
    __shared__ unsigned char sar[34 * 128];
    int bid = blockIdx.x;                  // 576 = 8*2*9*4
    int strip = bid & 3;
    int t = (bid >> 2) % 9;
    int c = (bid / 36) & 1;
    int bb = bid / 72;
    long off = (long)bb * BCH + (long)c * CHW;
    const float* vt = vox + off + (long)t * SLICE;
    int tn = (t + 1 < 9) ? t + 1 : 8;      // replication pad in T
    const float* vn = vox + off + (long)tn * SLICE;
    int y0 = strip * STRIP;
    // binarized slice rows gy in [y0-2, y0+34); zero outside image (zero-pad)
    for (int j = threadIdx.x; j < 36 * 128; j += 256) {
        int r = j >> 7, xx = j & 127;
        int gy = y0 - 2 + r;
        sbx[j] = ((unsigned)gy < 128u && vt[(gy << 7) + xx] > 0.0f) ? 1 : 0;
    }
    __syncthreads();
    // around rows ra in [0,34) <-> gy = y0-1+ra
    for (int j = threadIdx.x; j < 34 * 128; j += 256) {
        int ra = j >> 7, xx = j & 127;
        int gy = y0 - 1 + ra;
        unsigned char v = 0;
        if ((unsigned)gy < 128u) {
            int s = 0;
            for (int rs = ra; rs <= ra + 2; ++rs)
                for (int dx = -1; dx <= 1; ++dx) {
                    int x2 = xx + dx; if ((unsigned)x2 >= 128u) continue;
                    s += sbx[(rs << 7) + x2];
                }
            // prev*bxn > 4/9  <=>  bxn==1 && boxsum >= 5  (exact integer form)
            v = (vn[(gy << 7) + xx] > 0.0f && s >= 5) ? 1 : 0;
        }
        sar[j] = v;
    }
    __syncthreads();
    float* mt = mask + off + (long)t * SLICE;
    for (int j = threadIdx.x; j < STRIP * 128; j += 256) {
        int q = j >> 7, xx = j & 127;
        int s = 0;
        for (int ra = q; ra <= q + 2; ++ra)
            for (int dx = -1; dx <= 1; ++dx) {
                int x2 = xx + dx; if ((unsigned)x2 >= 128u) continue;
                s += sar[(ra << 7) + x2];
            }
        mt[((y0 + q) << 7) + xx] = (float)s / 9.0f;
    }
}

// ---------------- K5: fold stats + collapse conv1/dyn/conv3 to K[2][2][3] --
__global__ void k_prep(const float* __restrict__ conv1_w, const float* __restrict__ dyn_w,
                       const float* __restrict__ conv3_w, const float* __restrict__ s1,
                       float* __restrict__ nrm, float* __restrict__ Kc) {
    int tid = threadIdx.x;
    if (tid < 16) {
        float m = s1[tid] * INV_M;
        float var = s1[16 + tid] * INV_M - m * m;
        float inv = rsqrtf(var + 1e-5f);
        nrm[tid] = inv;
        nrm[16 + tid] = -m * inv;
    }
    if (tid < 12) {
        int d = tid % 3, c = (tid / 3) & 1, o2 = tid / 6;
        float acc = 0.0f;
        for (int o = 0; o < 16; ++o) {
            float c3 = conv3_w[o2 * 16 + o];
            for (int i = 0; i < 16; ++i) {
                float wsum = 0.0f;
                for (int k = 0; k < 4; ++k) wsum += dyn_w[((k * 16 + o) * 16 + i) * 3 + d];
                acc += c3 * (0.25f * wsum) * conv1_w[i * 2 + c];
                // attention is exactly uniform: pooled mean of inorm output is 0
            }
        }
        Kc[tid] = acc;            // Kc[o2*6 + c*3 + d]
    }
}

// ---------------- K6: whole t-column per thread: ILP/MLP -------------------
__global__ void __launch_bounds__(256) k_g(
        const float* __restrict__ vox, float* __restrict__ gm,
        const float* __restrict__ nrm, const float* __restrict__ Kc,
        float* __restrict__ s2) {
    int idx = blockIdx.x * 256 + threadIdx.x;   // (b,o2,hw): 8*2*16384 threads
    int hw = idx & (SLICE - 1);
    int o2 = (idx >> 14) & 1;
    int bb = idx >> 15;
    const float* v0 = vox + (size_t)bb * BCH + hw;       // c=0 column
    const float* v1 = v0 + CHW;                          // c=1 column
    float* go = gm + (size_t)bb * BCH + (size_t)o2 * CHW + hw;
    float a[9], d[9], m[9];
    #pragma unroll
    for (int tt = 0; tt < 9; ++tt) a[tt] = v0[tt * SLICE];
    #pragma unroll
    for (int tt = 0; tt < 9; ++tt) d[tt] = v1[tt * SLICE];
    #pragma unroll
    for (int tt = 0; tt < 9; ++tt) m[tt] = go[tt * SLICE];
    float sc0 = nrm[bb * 2], sh0 = nrm[16 + bb * 2];
    float sc1 = nrm[bb * 2 + 1], sh1 = nrm[16 + bb * 2 + 1];
    float k00 = Kc[o2 * 6 + 0], k01 = Kc[o2 * 6 + 1], k02 = Kc[o2 * 6 + 2];
    float k10 = Kc[o2 * 6 + 3], k11 = Kc[o2 * 6 + 4], k12 = Kc[o2 * 6 + 5];
    #pragma unroll
    for (int tt = 0; tt < 9; ++tt) { a[tt] = a[tt] * sc0 + sh0; d[tt] = d[tt] * sc1 + sh1; }
    float ls = 0.f, lq = 0.f;
    #pragma unroll
    for (int tt = 0; tt < 9; ++tt) {
        float pre = k01 * a[tt] + k11 * d[tt];
        if (tt > 0) pre += k00 * a[tt - 1] + k10 * d[tt - 1];
        if (tt < 8) pre += k02 * a[tt + 1] + k12 * d[tt + 1];
        float sig = 1.0f / (1.0f + expf(-pre));
        float g = sig * m[tt];
        go[tt * SLICE] = g;
        ls += g; lq += g * g;
    }
    __shared__ float ss[256], sq[256];
    ss[threadIdx.x] = ls; sq[threadIdx.x] = lq;
    __syncthreads();
    for (int ofs = 128; ofs > 0; ofs >>= 1) {
        if (threadIdx.x < ofs) { ss[threadIdx.x] += ss[threadIdx.x + ofs]; sq[threadIdx.x] += sq[threadIdx.x + ofs]; }
        __syncthreads();
    }
    if (threadIdx.x == 0) {
        int bc = bb * 2 + o2;
        atomicAdd(&s2[bc], ss[0]); atomicAdd(&s2[16 + bc], sq[0]);
    }
}

// ---------------- K7: final instance norm in place (float4) ----------------
__global__ void k_norm(float* __restrict__ out, const float* __restrict__ s2) {
    int i4 = blockIdx.x * 256 + threadIdx.x;    // grid = TOT/1024
    int bc = i4 / (CHW / 4);
    float m = s2[bc] * INV_M;
    float var = s2[16 + bc] * INV_M - m * m;
    float inv = rsqrtf(var + 1e-5f);
    float4 v = ((float4*)out)[i4];
    v.x = (v.x - m) * inv; v.y = (v.y - m) * inv;
    v.z = (v.z - m) * inv; v.w = (v.w - m) * inv;
    ((float4*)out)[i4] = v;
}

extern "C" void kernel_launch(void* const* d_in, const int* in_sizes, int n_in,
                              void* d_out, int out_size, void* d_ws, size_t ws_size,
                              hipStream_t stream) {
    const float* t  = (const float*)d_in[0];
    const int*   x  = (const int*)d_in[1];
    const int*   y  = (const int*)d_in[2];
    const int*   p  = (const int*)d_in[3];
    const int*   b  = (const int*)d_in[4];
    const float* conv1_w = (const float*)d_in[5];
    // d_in[6], d_in[7] (fc1_w, fc2_w): unused — attention is exactly uniform
    const float* dyn_w   = (const float*)d_in[8];
    const float* conv3_w = (const float*)d_in[9];
    float* out = (float*)d_out;
    int n = in_sizes[0];

    long availF = (long)(ws_size / sizeof(float));
    long needPack = (long)TOT + 2L * n + 128;    // vox + rec + tail
    int usePack = (availF >= needPack);
    int E;
    if (usePack) {
        long extra = (availF - needPack) / TOT;  // how many part buffers fit
        E = extra >= 2 ? (extra > 4 ? 4 : (int)extra) : 1;
    } else {
        long extra = (availF - ((long)TOT + 128)) / TOT;
        E = extra >= 2 ? (extra > 4 ? 4 : (int)extra) : 1;
    }

    float* ws   = (float*)d_ws;
    float* vox  = ws;                                        // TOT
    int2*  rec  = (int2*)(ws + TOT);                         // 2n ints (pack)
    float* part = ws + TOT + (usePack ? 2L * n : 0);         // E*TOT if E>1
    float* tail = part + (E > 1 ? (long)E * TOT : 0);
    unsigned* gmax  = (unsigned*)tail;                       // 8
    float*    s1    = tail + 8;                              // 32
    float*    nrm   = tail + 40;                             // 32
    float*    Kc    = tail + 72;                             // 12
    float*    s2    = tail + 84;                             // 32
    int*      start = (int*)(tail + 116);                    // 9

    hipMemsetAsync(tail, 0, 128 * sizeof(float), stream);

    k_bounds<<<1, 64, 0, stream>>>(b, start, n);
    k_tmax<<<2048, 256, 0, stream>>>(t, start, gmax);
    if (usePack) {
        k_pack<<<2048, 256, 0, stream>>>(t, x, y, p, gmax, start, rec);
        k_scat_p<<<dim3(9, 8, E), 512, 0, stream>>>(rec, start, vox, part, E);
    } else {
        k_scat<<<dim3(9, 8, E), 512, 0, stream>>>(t, x, y, p, gmax, start, vox, part, E);
    }
    if (E > 1) k_merge<<<TOT / 1024, 256, 0, stream>>>(part, vox, s1, E);
    else       k_stats1<<<512, 256, 0, stream>>>(vox, s1);
    k_mask<<<576, 256, 0, stream>>>(vox, out);               // d_out holds mask
    k_prep<<<1, 64, 0, stream>>>(conv1_w, dyn_w, conv3_w, s1, nrm, Kc);
    k_g<<<1024, 256, 0, stream>>>(vox, out, nrm, Kc, s2);
    k_norm<<<TOT / 1024, 256, 0, stream>>>(out, s2);
}

// Round 5
// 255.578 us; speedup vs baseline: 3.1866x; 1.5692x over previous
//
#include <hip/hip_runtime.h>
#include <math.h>

#define TT 9
#define HH 128
#define WW 128
#define BB 8
#define SLICE (HH*WW)           // 16384
#define CHW (TT*SLICE)          // 147456
#define BCH (2*CHW)             // 294912
#define TOT (BB*BCH)            // 2359296
#define INV_M (1.0f/147456.0f)

// ---------------- K0: batch start offsets via binary search (b sorted) -----
__global__ void k_bounds(const int* __restrict__ b, int* __restrict__ start, int n) {
    int tid = threadIdx.x;
    if (tid > 8) return;
    if (tid == 0) { start[0] = 0; return; }
    if (tid == 8) { start[8] = n; return; }
    int lo = 0, hi = n;
    while (lo < hi) { int mid = (lo + hi) >> 1; if (b[mid] < tid) lo = mid + 1; else hi = mid; }
    start[tid] = lo;
}

// ---------------- K1: per-batch max of t -----------------------------------
__global__ void k_tmax(const float* __restrict__ t, const int* __restrict__ start,
                       unsigned* __restrict__ gmax) {
    __shared__ unsigned sm[256];
    int bi = blockIdx.x & 7;
    int cj = blockIdx.x >> 3;
    int nb = gridDim.x >> 3;
    int s = start[bi], e = start[bi + 1];
    int len = e - s;
    if (len <= 0) return;
    int per = (len + nb - 1) / nb;
    int lo = s + cj * per;
    int hi = lo + per < e ? lo + per : e;
    unsigned m = 0u;
    for (int i = lo + threadIdx.x; i < hi; i += 256) {
        unsigned tv = __float_as_uint(t[i]);   // t >= 0: uint order == float order
        if (tv > m) m = tv;
    }
    sm[threadIdx.x] = m;
    __syncthreads();
    for (int ofs = 128; ofs > 0; ofs >>= 1) {
        if (threadIdx.x < ofs && sm[threadIdx.x + ofs] > sm[threadIdx.x])
            sm[threadIdx.x] = sm[threadIdx.x + ofs];
        __syncthreads();
    }
    if (threadIdx.x == 0 && sm[0]) atomicMax(&gmax[bi], sm[0]);
}

// ---------------- K1b: pack events to 8B records (ts bits, hw|p key) -------
__global__ void k_pack(const float* __restrict__ t, const int* __restrict__ x,
                       const int* __restrict__ y, const int* __restrict__ p,
                       const unsigned* __restrict__ gmax, const int* __restrict__ start,
                       int2* __restrict__ rec) {
    int bi = blockIdx.x & 7;
    int cj = blockIdx.x >> 3;
    int nb = gridDim.x >> 3;
    int s = start[bi], e = start[bi + 1];
    int len = e - s;
    if (len <= 0) return;
    int per = (len + nb - 1) / nb;
    int lo = s + cj * per;
    int hi = lo + per < e ? lo + per : e;
    float tmax = __uint_as_float(gmax[bi]);
    int i = lo + threadIdx.x;
    for (; i + 256 < hi; i += 512) {
        float t0 = t[i],  t1 = t[i + 256];
        int   x0 = x[i],  x1 = x[i + 256];
        int   y0 = y[i],  y1 = y[i + 256];
        int   p0 = p[i],  p1 = p[i + 256];
        float ts0 = t0 / tmax * 9.0f;            // same op order as reference
        float ts1 = t1 / tmax * 9.0f;
        rec[i]       = make_int2(__float_as_int(ts0), x0 + (y0 << 7) + (p0 << 14));
        rec[i + 256] = make_int2(__float_as_int(ts1), x1 + (y1 << 7) + (p1 << 14));
    }
    for (; i < hi; i += 256) {
        float ts = t[i] / tmax * 9.0f;
        rec[i] = make_int2(__float_as_int(ts), x[i] + (y[i] << 7) + (p[i] << 14));
    }
}

// ---------------- K2: scatter via per-(b,t) LDS slice ownership (packed) ---
// 1024 threads, 8x unrolled scan: >=8 independent loads in flight per wave.
#define SCAT_BODY(r)                                                        \
    {   float ts = __int_as_float((r).x);                                   \
        float fl = floorf(ts);                                              \
        int i0 = (int)fl;                                                   \
        bool h0 = (i0 == tg), h1 = (i0 + 1 == tg);                          \
        if (h0 | h1) {                                                      \
            float w = h0 ? (1.0f - (ts - fl)) : (1.0f - (ftg - ts));        \
            atomicAdd(&sl[(r).y], w);                                       \
        } }

__global__ void __launch_bounds__(1024, 4) k_scat_p(
        const int2* __restrict__ rec, const int* __restrict__ start,
        float* __restrict__ vox, float* __restrict__ part, int E) {
    __shared__ float sl[2 * SLICE];              // 128 KiB
    int tg = blockIdx.x, bb = blockIdx.y, e = blockIdx.z;
    int s = start[bb], en = start[bb + 1];
    long len = en - s;
    int cs = s + (int)(len * e / E);
    int ce = s + (int)(len * (e + 1) / E);
    for (int j = threadIdx.x; j < 2 * SLICE; j += 1024) sl[j] = 0.0f;
    __syncthreads();
    float ftg = (float)tg;
    int i = cs + threadIdx.x;
    for (; i + 7 * 1024 < ce; i += 8 * 1024) {
        int2 r0 = rec[i];
        int2 r1 = rec[i + 1024];
        int2 r2 = rec[i + 2 * 1024];
        int2 r3 = rec[i + 3 * 1024];
        int2 r4 = rec[i + 4 * 1024];
        int2 r5 = rec[i + 5 * 1024];
        int2 r6 = rec[i + 6 * 1024];
        int2 r7 = rec[i + 7 * 1024];
        SCAT_BODY(r0) SCAT_BODY(r1) SCAT_BODY(r2) SCAT_BODY(r3)
        SCAT_BODY(r4) SCAT_BODY(r5) SCAT_BODY(r6) SCAT_BODY(r7)
    }
    for (; i < ce; i += 1024) { int2 r = rec[i]; SCAT_BODY(r) }
    __syncthreads();
    float* dst = (E > 1 ? part + (size_t)e * TOT : vox)
               + (size_t)bb * BCH + (size_t)tg * SLICE;
    for (int j = threadIdx.x; j < SLICE; j += 1024) {
        dst[j]       = sl[j];
        dst[CHW + j] = sl[SLICE + j];
    }
}

// ---------------- K2 fallback: unpacked event scan (same unroll) -----------
__global__ void __launch_bounds__(1024, 4) k_scat(
        const float* __restrict__ t, const int* __restrict__ x,
        const int* __restrict__ y, const int* __restrict__ p,
        const unsigned* __restrict__ gmax, const int* __restrict__ start,
        float* __restrict__ vox, float* __restrict__ part, int E) {
    __shared__ float sl[2 * SLICE];
    int tg = blockIdx.x, bb = blockIdx.y, e = blockIdx.z;
    int s = start[bb], en = start[bb + 1];
    long len = en - s;
    int cs = s + (int)(len * e / E);
    int ce = s + (int)(len * (e + 1) / E);
    for (int j = threadIdx.x; j < 2 * SLICE; j += 1024) sl[j] = 0.0f;
    __syncthreads();
    float tmax = __uint_as_float(gmax[bb]);
    float ftg = (float)tg;
    for (int i = cs + threadIdx.x; i < ce; i += 1024) {
        float ts = t[i] / tmax * 9.0f;
        float fl = floorf(ts);
        int i0 = (int)fl;
        bool h0 = (i0 == tg), h1 = (i0 + 1 == tg);
        if (h0 | h1) {
            float w = h0 ? (1.0f - (ts - fl)) : (1.0f - (ftg - ts));
            int hw = x[i] + (y[i] << 7) + (p[i] << 14);
            atomicAdd(&sl[hw], w);
        }
    }
    __syncthreads();
    float* dst = (E > 1 ? part + (size_t)e * TOT : vox)
               + (size_t)bb * BCH + (size_t)tg * SLICE;
    for (int j = threadIdx.x; j < SLICE; j += 1024) {
        dst[j]       = sl[j];
        dst[CHW + j] = sl[SLICE + j];
    }
}

// ---------------- K2b: merge E partials + inorm stats (E>1 path) -----------
__global__ void k_merge(const float* __restrict__ part, float* __restrict__ vox,
                        float* __restrict__ s1, int E) {
    __shared__ float ss[256], sq[256];
    int i4 = blockIdx.x * 256 + threadIdx.x;     // float4 index; grid=TOT/1024
    const float4* pp = (const float4*)part;
    float4 a = pp[i4];
    for (int e = 1; e < E; ++e) {
        float4 v = pp[(size_t)e * (TOT / 4) + i4];
        a.x += v.x; a.y += v.y; a.z += v.z; a.w += v.w;
    }
    ((float4*)vox)[i4] = a;
    ss[threadIdx.x] = a.x + a.y + a.z + a.w;
    sq[threadIdx.x] = a.x * a.x + a.y * a.y + a.z * a.z + a.w * a.w;
    __syncthreads();
    for (int ofs = 128; ofs > 0; ofs >>= 1) {
        if (threadIdx.x < ofs) { ss[threadIdx.x] += ss[threadIdx.x + ofs]; sq[threadIdx.x] += sq[threadIdx.x + ofs]; }
        __syncthreads();
    }
    if (threadIdx.x == 0) {
        int bc = i4 / (CHW / 4);
        atomicAdd(&s1[bc], ss[0]); atomicAdd(&s1[16 + bc], sq[0]);
    }
}

// ---------------- K3: per-(b,c) sum / sumsq of vox (E==1 path) -------------
__global__ void k_stats1(const float* __restrict__ vox, float* __restrict__ s1) {
    __shared__ float ss[256], sq[256];
    int bc = blockIdx.x >> 5, part = blockIdx.x & 31;
    const float4* vp = (const float4*)(vox + (long)bc * CHW);
    const int per = (CHW / 4) / 32;
    float s = 0.f, q = 0.f;
    for (int j = part * per + threadIdx.x; j < (part + 1) * per; j += 256) {
        float4 v = vp[j];
        s += v.x + v.y + v.z + v.w;
        q += v.x * v.x + v.y * v.y + v.z * v.z + v.w * v.w;
    }
    ss[threadIdx.x] = s; sq[threadIdx.x] = q;
    __syncthreads();
    for (int ofs = 128; ofs > 0; ofs >>= 1) {
        if (threadIdx.x < ofs) { ss[threadIdx.x] += ss[threadIdx.x + ofs]; sq[threadIdx.x] += sq[threadIdx.x + ofs]; }
        __syncthreads();
    }
    if (threadIdx.x == 0) { atomicAdd(&s1[bc], ss[0]); atomicAdd(&s1[16 + bc], sq[0]); }
}

// ---------------- K4: time-corr mask, y-strip parallel (576 blocks) --------
#define STRIP 32
__global__ void k_mask(const float* __restrict__ vox, float* __restrict__ mask) {
    __shared__ unsigned char sbx[36 * 128];
    __shared__ unsigned char sar[34 * 128];
    int bid = blockIdx.x;                  // 576 = 8*2*9*4
    int strip = bid & 3;
    int t = (bid >> 2) % 9;
    int c = (bid / 36) & 1;
    int bb = bid / 72;
    long off = (long)bb * BCH + (long)c * CHW;
    const float* vt = vox + off + (long)t * SLICE;
    int tn = (t + 1 < 9) ? t + 1 : 8;      // replication pad in T
    const float* vn = vox + off + (long)tn * SLICE;
    int y0 = strip * STRIP;
    for (int j = threadIdx.x; j < 36 * 128; j += 256) {
        int r = j >> 7, xx = j & 127;
        int gy = y0 - 2 + r;
        sbx[j] = ((unsigned)gy < 128u && vt[(gy << 7) + xx] > 0.0f) ? 1 : 0;
    }
    __syncthreads();
    for (int j = threadIdx.x; j < 34 * 128; j += 256) {
        int ra = j >> 7, xx = j & 127;
        int gy = y0 - 1 + ra;
        unsigned char v = 0;
        if ((unsigned)gy < 128u) {
            int s = 0;
            for (int rs = ra; rs <= ra + 2; ++rs)
                for (int dx = -1; dx <= 1; ++dx) {
                    int x2 = xx + dx; if ((unsigned)x2 >= 128u) continue;
                    s += sbx[(rs << 7) + x2];
                }
            // prev*bxn > 4/9  <=>  bxn==1 && boxsum >= 5  (exact integer form)
            v = (vn[(gy << 7) + xx] > 0.0f && s >= 5) ? 1 : 0;
        }
        sar[j] = v;
    }
    __syncthreads();
    float* mt = mask + off + (long)t * SLICE;
    for (int j = threadIdx.x; j < STRIP * 128; j += 256) {
        int q = j >> 7, xx = j & 127;
        int s = 0;
        for (int ra = q; ra <= q + 2; ++ra)
            for (int dx = -1; dx <= 1; ++dx) {
                int x2 = xx + dx; if ((unsigned)x2 >= 128u) continue;
                s += sar[(ra << 7) + x2];
            }
        mt[((y0 + q) << 7) + xx] = (float)s / 9.0f;
    }
}

// ---------------- K5: fold stats + collapse conv1/dyn/conv3 to K[2][2][3] --
__global__ void k_prep(const float* __restrict__ conv1_w, const float* __restrict__ dyn_w,
                       const float* __restrict__ conv3_w, const float* __restrict__ s1,
                       float* __restrict__ nrm, float* __restrict__ Kc) {
    int tid = threadIdx.x;
    if (tid < 16) {
        float m = s1[tid] * INV_M;
        float var = s1[16 + tid] * INV_M - m * m;
        float inv = rsqrtf(var + 1e-5f);
        nrm[tid] = inv;
        nrm[16 + tid] = -m * inv;
    }
    if (tid < 12) {
        int d = tid % 3, c = (tid / 3) & 1, o2 = tid / 6;
        float acc = 0.0f;
        for (int o = 0; o < 16; ++o) {
            float c3 = conv3_w[o2 * 16 + o];
            for (int i = 0; i < 16; ++i) {
                float wsum = 0.0f;
                for (int k = 0; k < 4; ++k) wsum += dyn_w[((k * 16 + o) * 16 + i) * 3 + d];
                acc += c3 * (0.25f * wsum) * conv1_w[i * 2 + c];
                // attention is exactly uniform: pooled mean of inorm output is 0
            }
        }
        Kc[tid] = acc;            // Kc[o2*6 + c*3 + d]
    }
}

// ---------------- K6: whole t-column per thread: ILP/MLP -------------------
__global__ void __launch_bounds__(256) k_g(
        const float* __restrict__ vox, float* __restrict__ gm,
        const float* __restrict__ nrm, const float* __restrict__ Kc,
        float* __restrict__ s2) {
    int idx = blockIdx.x * 256 + threadIdx.x;   // (b,o2,hw): 8*2*16384 threads
    int hw = idx & (SLICE - 1);
    int o2 = (idx >> 14) & 1;
    int bb = idx >> 15;
    const float* v0 = vox + (size_t)bb * BCH + hw;       // c=0 column
    const float* v1 = v0 + CHW;                          // c=1 column
    float* go = gm + (size_t)bb * BCH + (size_t)o2 * CHW + hw;
    float a[9], d[9], m[9];
    #pragma unroll
    for (int tt = 0; tt < 9; ++tt) a[tt] = v0[tt * SLICE];
    #pragma unroll
    for (int tt = 0; tt < 9; ++tt) d[tt] = v1[tt * SLICE];
    #pragma unroll
    for (int tt = 0; tt < 9; ++tt) m[tt] = go[tt * SLICE];
    float sc0 = nrm[bb * 2], sh0 = nrm[16 + bb * 2];
    float sc1 = nrm[bb * 2 + 1], sh1 = nrm[16 + bb * 2 + 1];
    float k00 = Kc[o2 * 6 + 0], k01 = Kc[o2 * 6 + 1], k02 = Kc[o2 * 6 + 2];
    float k10 = Kc[o2 * 6 + 3], k11 = Kc[o2 * 6 + 4], k12 = Kc[o2 * 6 + 5];
    #pragma unroll
    for (int tt = 0; tt < 9; ++tt) { a[tt] = a[tt] * sc0 + sh0; d[tt] = d[tt] * sc1 + sh1; }
    float ls = 0.f, lq = 0.f;
    #pragma unroll
    for (int tt = 0; tt < 9; ++tt) {
        float pre = k01 * a[tt] + k11 * d[tt];
        if (tt > 0) pre += k00 * a[tt - 1] + k10 * d[tt - 1];
        if (tt < 8) pre += k02 * a[tt + 1] + k12 * d[tt + 1];
        float sig = 1.0f / (1.0f + expf(-pre));
        float g = sig * m[tt];
        go[tt * SLICE] = g;
        ls += g; lq += g * g;
    }
    __shared__ float ss[256], sq[256];
    ss[threadIdx.x] = ls; sq[threadIdx.x] = lq;
    __syncthreads();
    for (int ofs = 128; ofs > 0; ofs >>= 1) {
        if (threadIdx.x < ofs) { ss[threadIdx.x] += ss[threadIdx.x + ofs]; sq[threadIdx.x] += sq[threadIdx.x + ofs]; }
        __syncthreads();
    }
    if (threadIdx.x == 0) {
        int bc = bb * 2 + o2;
        atomicAdd(&s2[bc], ss[0]); atomicAdd(&s2[16 + bc], sq[0]);
    }
}

// ---------------- K7: final instance norm in place (float4) ----------------
__global__ void k_norm(float* __restrict__ out, const float* __restrict__ s2) {
    int i4 = blockIdx.x * 256 + threadIdx.x;    // grid = TOT/1024
    int bc = i4 / (CHW / 4);
    float m = s2[bc] * INV_M;
    float var = s2[16 + bc] * INV_M - m * m;
    float inv = rsqrtf(var + 1e-5f);
    float4 v = ((float4*)out)[i4];
    v.x = (v.x - m) * inv; v.y = (v.y - m) * inv;
    v.z = (v.z - m) * inv; v.w = (v.w - m) * inv;
    ((float4*)out)[i4] = v;
}

extern "C" void kernel_launch(void* const* d_in, const int* in_sizes, int n_in,
                              void* d_out, int out_size, void* d_ws, size_t ws_size,
                              hipStream_t stream) {
    const float* t  = (const float*)d_in[0];
    const int*   x  = (const int*)d_in[1];
    const int*   y  = (const int*)d_in[2];
    const int*   p  = (const int*)d_in[3];
    const int*   b  = (const int*)d_in[4];
    const float* conv1_w = (const float*)d_in[5];
    // d_in[6], d_in[7] (fc1_w, fc2_w): unused — attention is exactly uniform
    const float* dyn_w   = (const float*)d_in[8];
    const float* conv3_w = (const float*)d_in[9];
    float* out = (float*)d_out;
    int n = in_sizes[0];

    long availF = (long)(ws_size / sizeof(float));
    long needPack = (long)TOT + 2L * n + 128;    // vox + rec + tail
    int usePack = (availF >= needPack);
    int E;
    if (usePack) {
        long extra = (availF - needPack) / TOT;  // how many part buffers fit
        E = extra >= 2 ? (extra > 4 ? 4 : (int)extra) : 1;
    } else {
        long extra = (availF - ((long)TOT + 128)) / TOT;
        E = extra >= 2 ? (extra > 4 ? 4 : (int)extra) : 1;
    }

    float* ws   = (float*)d_ws;
    float* vox  = ws;                                        // TOT
    int2*  rec  = (int2*)(ws + TOT);                         // 2n ints (pack)
    float* part = ws + TOT + (usePack ? 2L * n : 0);         // E*TOT if E>1
    float* tail = part + (E > 1 ? (long)E * TOT : 0);
    unsigned* gmax  = (unsigned*)tail;                       // 8
    float*    s1    = tail + 8;                              // 32
    float*    nrm   = tail + 40;                             // 32
    float*    Kc    = tail + 72;                             // 12
    float*    s2    = tail + 84;                             // 32
    int*      start = (int*)(tail + 116);                    // 9

    hipMemsetAsync(tail, 0, 128 * sizeof(float), stream);

    k_bounds<<<1, 64, 0, stream>>>(b, start, n);
    k_tmax<<<2048, 256, 0, stream>>>(t, start, gmax);
    if (usePack) {
        k_pack<<<2048, 256, 0, stream>>>(t, x, y, p, gmax, start, rec);
        k_scat_p<<<dim3(9, 8, E), 1024, 0, stream>>>(rec, start, vox, part, E);
    } else {
        k_scat<<<dim3(9, 8, E), 1024, 0, stream>>>(t, x, y, p, gmax, start, vox, part, E);
    }
    if (E > 1) k_merge<<<TOT / 1024, 256, 0, stream>>>(part, vox, s1, E);
    else       k_stats1<<<512, 256, 0, stream>>>(vox, s1);
    k_mask<<<576, 256, 0, stream>>>(vox, out);               // d_out holds mask
    k_prep<<<1, 64, 0, stream>>>(conv1_w, dyn_w, conv3_w, s1, nrm, Kc);
    k_g<<<1024, 256, 0, stream>>>(vox, out, nrm, Kc, s2);
    k_norm<<<TOT / 1024, 256, 0, stream>>>(out, s2);
}

// Round 6
// 240.044 us; speedup vs baseline: 3.3929x; 1.0647x over previous
//
#include <hip/hip_runtime.h>
#include <math.h>

#define TT 9
#define HH 128
#define WW 128
#define BB 8
#define SLICE (HH*WW)           // 16384
#define CHW (TT*SLICE)          // 147456
#define BCH (2*CHW)             // 294912
#define TOT (BB*BCH)            // 2359296
#define INV_M (1.0f/147456.0f)
#define NBK 36                  // 9 t-bins x 4 y-quarters per batch

// ---------------- K0: batch start offsets via binary search (b sorted) -----
__global__ void k_bounds(const int* __restrict__ b, int* __restrict__ start, int n) {
    int tid = threadIdx.x;
    if (tid > 8) return;
    if (tid == 0) { start[0] = 0; return; }
    if (tid == 8) { start[8] = n; return; }
    int lo = 0, hi = n;
    while (lo < hi) { int mid = (lo + hi) >> 1; if (b[mid] < tid) lo = mid + 1; else hi = mid; }
    start[tid] = lo;
}

// ---------------- K1: per-batch max of t -----------------------------------
__global__ void k_tmax(const float* __restrict__ t, const int* __restrict__ start,
                       unsigned* __restrict__ gmax) {
    __shared__ unsigned sm[256];
    int bi = blockIdx.x & 7;
    int cj = blockIdx.x >> 3;
    int nb = gridDim.x >> 3;
    int s = start[bi], e = start[bi + 1];
    int len = e - s;
    if (len <= 0) return;
    int per = (len + nb - 1) / nb;
    int lo = s + cj * per;
    int hi = lo + per < e ? lo + per : e;
    unsigned m = 0u;
    for (int i = lo + threadIdx.x; i < hi; i += 256) {
        unsigned tv = __float_as_uint(t[i]);   // t >= 0: uint order == float order
        if (tv > m) m = tv;
    }
    sm[threadIdx.x] = m;
    __syncthreads();
    for (int ofs = 128; ofs > 0; ofs >>= 1) {
        if (threadIdx.x < ofs && sm[threadIdx.x + ofs] > sm[threadIdx.x])
            sm[threadIdx.x] = sm[threadIdx.x + ofs];
        __syncthreads();
    }
    if (threadIdx.x == 0 && sm[0]) atomicMax(&gmax[bi], sm[0]);
}

// ---------------- K2a: histogram of (t-bin, y-quarter) per batch -----------
__global__ void __launch_bounds__(256) k_hist(
        const float* __restrict__ t, const int* __restrict__ y,
        const unsigned* __restrict__ gmax, const int* __restrict__ start,
        unsigned* __restrict__ hist) {
    __shared__ unsigned lh[NBK];
    int bi = blockIdx.x & 7, cj = blockIdx.x >> 3, nb = gridDim.x >> 3;
    int s = start[bi], e = start[bi + 1], len = e - s;
    if (threadIdx.x < NBK) lh[threadIdx.x] = 0u;
    __syncthreads();
    if (len > 0) {
        int per = (len + nb - 1) / nb;
        int lo = s + cj * per;
        int hi = lo + per < e ? lo + per : e;
        float tmax = __uint_as_float(gmax[bi]);
        #pragma unroll 2
        for (int i = lo + threadIdx.x; i < hi; i += 256) {
            float ts = t[i] / tmax * 9.0f;       // same op order as reference
            int i0 = (int)floorf(ts);
            if ((unsigned)i0 < 9u) atomicAdd(&lh[i0 * 4 + (y[i] >> 5)], 1u);
        }
    }
    __syncthreads();
    if (threadIdx.x < NBK) {
        unsigned c = lh[threadIdx.x];
        if (c) atomicAdd(&hist[bi * NBK + threadIdx.x], c);
    }
}

// ---------------- K2b: exclusive scan -> segment bases + working cursors ---
__global__ void k_scan(const int* __restrict__ start, const unsigned* __restrict__ hist,
                       unsigned* __restrict__ segbase, unsigned* __restrict__ cursor) {
    int b = threadIdx.x;
    if (b < 8) {
        unsigned base = (unsigned)start[b];
        for (int lb = 0; lb < NBK; ++lb) {
            segbase[b * NBK + lb] = base;
            cursor[b * NBK + lb] = base;
            base += hist[b * NBK + lb];
        }
    }
}

// ---------------- K2c: place records into bucket segments ------------------
__global__ void __launch_bounds__(256) k_place(
        const float* __restrict__ t, const int* __restrict__ x,
        const int* __restrict__ y, const int* __restrict__ p,
        const unsigned* __restrict__ gmax, const int* __restrict__ start,
        unsigned* __restrict__ cursor, int2* __restrict__ rec) {
    __shared__ unsigned lh[NBK];
    __shared__ unsigned lc[NBK];
    int bi = blockIdx.x & 7, cj = blockIdx.x >> 3, nb = gridDim.x >> 3;
    int s = start[bi], e = start[bi + 1], len = e - s;
    if (len <= 0) return;
    int per = (len + nb - 1) / nb;
    int lo = s + cj * per;
    int hi = lo + per < e ? lo + per : e;
    float tmax = __uint_as_float(gmax[bi]);
    for (int base = lo; base < hi; base += 2048) {
        if (threadIdx.x < NBK) lh[threadIdx.x] = 0u;
        __syncthreads();
        int lb[8]; float tsv[8]; int keyv[8];
        #pragma unroll
        for (int k = 0; k < 8; ++k) {
            int idx = base + (k << 8) + threadIdx.x;
            lb[k] = -1; tsv[k] = 0.f; keyv[k] = 0;
            if (idx < hi) {
                float ts = t[idx] / tmax * 9.0f;     // same op order as reference
                int yy = y[idx];
                int i0 = (int)floorf(ts);
                if ((unsigned)i0 < 9u) {
                    lb[k] = i0 * 4 + (yy >> 5);
                    tsv[k] = ts;
                    keyv[k] = x[idx] + (yy << 7) + (p[idx] << 14);
                }
            }
        }
        #pragma unroll
        for (int k = 0; k < 8; ++k)
            if (lb[k] >= 0) atomicAdd(&lh[lb[k]], 1u);
        __syncthreads();
        if (threadIdx.x < NBK) {
            unsigned c = lh[threadIdx.x];
            lc[threadIdx.x] = c ? atomicAdd(&cursor[bi * NBK + threadIdx.x], c) : 0u;
        }
        __syncthreads();
        #pragma unroll
        for (int k = 0; k < 8; ++k)
            if (lb[k] >= 0) {
                unsigned slot = atomicAdd(&lc[lb[k]], 1u);
                rec[slot] = make_int2(__float_as_int(tsv[k]), keyv[k]);
            }
        __syncthreads();
    }
}

// ---------------- K2d: bucketed scatter, direct vox write ------------------
// Block (tg, b, yq): owns vox[b][0..1][tg][yq*32..+32][*] in 32 KB LDS.
// Reads bucket (b,tg,yq) with w0 = 1-(ts-tg) and bucket (b,tg-1,yq) with
// w1 = 1-(tg-ts): every record accepted, zero filtering waste, no merge.
#define SCB(r, WEXPR)                                                       \
    {   float ts = __int_as_float((r).x);                                   \
        float w = (WEXPR);                                                  \
        int k = (r).y;                                                      \
        atomicAdd(&sl[(k & 0xFFF) | ((k >> 2) & 0x1000)], w); }

__global__ void __launch_bounds__(512) k_scat_b(
        const int2* __restrict__ rec, const unsigned* __restrict__ hist,
        const unsigned* __restrict__ segbase, float* __restrict__ vox) {
    __shared__ float sl[2 * 32 * 128];           // 32 KiB
    int tg = blockIdx.x, bb = blockIdx.y, yq = blockIdx.z;
    for (int j = threadIdx.x; j < 8192; j += 512) sl[j] = 0.0f;
    __syncthreads();
    float ftg = (float)tg;
    {   // lower-bin deposits: records with i0 == tg; fl == ftg exactly
        int lb = bb * NBK + tg * 4 + yq;
        unsigned sA = segbase[lb], eA = sA + hist[lb];
        unsigned i = sA + threadIdx.x;
        for (; i + 7 * 512 < eA; i += 8 * 512) {
            int2 r0 = rec[i],            r1 = rec[i + 512];
            int2 r2 = rec[i + 2 * 512],  r3 = rec[i + 3 * 512];
            int2 r4 = rec[i + 4 * 512],  r5 = rec[i + 5 * 512];
            int2 r6 = rec[i + 6 * 512],  r7 = rec[i + 7 * 512];
            SCB(r0, 1.0f - (ts - ftg)) SCB(r1, 1.0f - (ts - ftg))
            SCB(r2, 1.0f - (ts - ftg)) SCB(r3, 1.0f - (ts - ftg))
            SCB(r4, 1.0f - (ts - ftg)) SCB(r5, 1.0f - (ts - ftg))
            SCB(r6, 1.0f - (ts - ftg)) SCB(r7, 1.0f - (ts - ftg))
        }
        for (; i < eA; i += 512) { int2 r = rec[i]; SCB(r, 1.0f - (ts - ftg)) }
    }
    if (tg > 0) {  // upper-bin deposits: records with i0 == tg-1, i1 == tg
        int lb = bb * NBK + (tg - 1) * 4 + yq;
        unsigned sB = segbase[lb], eB = sB + hist[lb];
        unsigned i = sB + threadIdx.x;
        for (; i + 7 * 512 < eB; i += 8 * 512) {
            int2 r0 = rec[i],            r1 = rec[i + 512];
            int2 r2 = rec[i + 2 * 512],  r3 = rec[i + 3 * 512];
            int2 r4 = rec[i + 4 * 512],  r5 = rec[i + 5 * 512];
            int2 r6 = rec[i + 6 * 512],  r7 = rec[i + 7 * 512];
            SCB(r0, 1.0f - (ftg - ts)) SCB(r1, 1.0f - (ftg - ts))
            SCB(r2, 1.0f - (ftg - ts)) SCB(r3, 1.0f - (ftg - ts))
            SCB(r4, 1.0f - (ftg - ts)) SCB(r5, 1.0f - (ftg - ts))
            SCB(r6, 1.0f - (ftg - ts)) SCB(r7, 1.0f - (ftg - ts))
        }
        for (; i < eB; i += 512) { int2 r = rec[i]; SCB(r, 1.0f - (ftg - ts)) }
    }
    __syncthreads();
    float* d0 = vox + (size_t)bb * BCH + (size_t)tg * SLICE + (yq << 12);
    for (int j = threadIdx.x; j < 4096; j += 512) {
        d0[j]       = sl[j];          // p = 0
        d0[CHW + j] = sl[4096 + j];   // p = 1
    }
}

// ---------------- K2 fallback: unpacked 9x-rescan, direct vox --------------
__global__ void __launch_bounds__(1024, 4) k_scat(
        const float* __restrict__ t, const int* __restrict__ x,
        const int* __restrict__ y, const int* __restrict__ p,
        const unsigned* __restrict__ gmax, const int* __restrict__ start,
        float* __restrict__ vox) {
    __shared__ float sl[2 * SLICE];
    int tg = blockIdx.x, bb = blockIdx.y;
    int cs = start[bb], ce = start[bb + 1];
    for (int j = threadIdx.x; j < 2 * SLICE; j += 1024) sl[j] = 0.0f;
    __syncthreads();
    float tmax = __uint_as_float(gmax[bb]);
    float ftg = (float)tg;
    for (int i = cs + threadIdx.x; i < ce; i += 1024) {
        float ts = t[i] / tmax * 9.0f;
        float fl = floorf(ts);
        int i0 = (int)fl;
        bool h0 = (i0 == tg), h1 = (i0 + 1 == tg);
        if (h0 | h1) {
            float w = h0 ? (1.0f - (ts - fl)) : (1.0f - (ftg - ts));
            int hw = x[i] + (y[i] << 7) + (p[i] << 14);
            atomicAdd(&sl[hw], w);
        }
    }
    __syncthreads();
    float* dst = vox + (size_t)bb * BCH + (size_t)tg * SLICE;
    for (int j = threadIdx.x; j < SLICE; j += 1024) {
        dst[j]       = sl[j];
        dst[CHW + j] = sl[SLICE + j];
    }
}

// ---------------- K4: time-corr mask + fused inorm stats -------------------
#define STRIP 32
__global__ void k_mask(const float* __restrict__ vox, float* __restrict__ mask,
                       float* __restrict__ s1) {
    __shared__ unsigned char sbx[36 * 128];
    __shared__ unsigned char sar[34 * 128];
    __shared__ float red[256], red2[256];
    int bid = blockIdx.x;                  // 576 = 8*2*9*4
    int strip = bid & 3;
    int t = (bid >> 2) % 9;
    int c = (bid / 36) & 1;
    int bb = bid / 72;
    long off = (long)bb * BCH + (long)c * CHW;
    const float* vt = vox + off + (long)t * SLICE;
    int tn = (t + 1 < 9) ? t + 1 : 8;      // replication pad in T
    const float* vn = vox + off + (long)tn * SLICE;
    int y0 = strip * STRIP;
    float s_acc = 0.f, q_acc = 0.f;
    for (int j = threadIdx.x; j < 36 * 128; j += 256) {
        int r = j >> 7, xx = j & 127;
        int gy = y0 - 2 + r;
        float v = 0.f;
        bool in = (unsigned)gy < 128u;
        if (in) v = vt[(gy << 7) + xx];
        sbx[j] = (in && v > 0.0f) ? 1 : 0;
        if (r >= 2 && r < 34) { s_acc += v; q_acc += v * v; }  // owned rows
    }
    __syncthreads();
    for (int j = threadIdx.x; j < 34 * 128; j += 256) {
        int ra = j >> 7, xx = j & 127;
        int gy = y0 - 1 + ra;
        unsigned char v = 0;
        if ((unsigned)gy < 128u) {
            int s = 0;
            for (int rs = ra; rs <= ra + 2; ++rs)
                for (int dx = -1; dx <= 1; ++dx) {
                    int x2 = xx + dx; if ((unsigned)x2 >= 128u) continue;
                    s += sbx[(rs << 7) + x2];
                }
            // prev*bxn > 4/9  <=>  bxn==1 && boxsum >= 5  (exact integer form)
            v = (vn[(gy << 7) + xx] > 0.0f && s >= 5) ? 1 : 0;
        }
        sar[j] = v;
    }
    __syncthreads();
    float* mt = mask + off + (long)t * SLICE;
    for (int j = threadIdx.x; j < STRIP * 128; j += 256) {
        int q = j >> 7, xx = j & 127;
        int s = 0;
        for (int ra = q; ra <= q + 2; ++ra)
            for (int dx = -1; dx <= 1; ++dx) {
                int x2 = xx + dx; if ((unsigned)x2 >= 128u) continue;
                s += sar[(ra << 7) + x2];
            }
        mt[((y0 + q) << 7) + xx] = (float)s / 9.0f;
    }
    // fused per-(b,c) stats: every vox element summed exactly once
    red[threadIdx.x] = s_acc; red2[threadIdx.x] = q_acc;
    __syncthreads();
    for (int ofs = 128; ofs > 0; ofs >>= 1) {
        if (threadIdx.x < ofs) { red[threadIdx.x] += red[threadIdx.x + ofs]; red2[threadIdx.x] += red2[threadIdx.x + ofs]; }
        __syncthreads();
    }
    if (threadIdx.x == 0) {
        int bc = bb * 2 + c;
        atomicAdd(&s1[bc], red[0]); atomicAdd(&s1[16 + bc], red2[0]);
    }
}

// ---------------- K5: fold stats + collapse conv1/dyn/conv3 to K[2][2][3] --
__global__ void k_prep(const float* __restrict__ conv1_w, const float* __restrict__ dyn_w,
                       const float* __restrict__ conv3_w, const float* __restrict__ s1,
                       float* __restrict__ nrm, float* __restrict__ Kc) {
    int tid = threadIdx.x;
    if (tid < 16) {
        float m = s1[tid] * INV_M;
        float var = s1[16 + tid] * INV_M - m * m;
        float inv = rsqrtf(var + 1e-5f);
        nrm[tid] = inv;
        nrm[16 + tid] = -m * inv;
    }
    if (tid < 12) {
        int d = tid % 3, c = (tid / 3) & 1, o2 = tid / 6;
        float acc = 0.0f;
        for (int o = 0; o < 16; ++o) {
            float c3 = conv3_w[o2 * 16 + o];
            for (int i = 0; i < 16; ++i) {
                float wsum = 0.0f;
                for (int k = 0; k < 4; ++k) wsum += dyn_w[((k * 16 + o) * 16 + i) * 3 + d];
                acc += c3 * (0.25f * wsum) * conv1_w[i * 2 + c];
                // attention is exactly uniform: pooled mean of inorm output is 0
            }
        }
        Kc[tid] = acc;            // Kc[o2*6 + c*3 + d]
    }
}

// ---------------- K6: whole t-column per thread: ILP/MLP -------------------
__global__ void __launch_bounds__(256) k_g(
        const float* __restrict__ vox, float* __restrict__ gm,
        const float* __restrict__ nrm, const float* __restrict__ Kc,
        float* __restrict__ s2) {
    int idx = blockIdx.x * 256 + threadIdx.x;   // (b,o2,hw): 8*2*16384 threads
    int hw = idx & (SLICE - 1);
    int o2 = (idx >> 14) & 1;
    int bb = idx >> 15;
    const float* v0 = vox + (size_t)bb * BCH + hw;       // c=0 column
    const float* v1 = v0 + CHW;                          // c=1 column
    float* go = gm + (size_t)bb * BCH + (size_t)o2 * CHW + hw;
    float a[9], d[9], m[9];
    #pragma unroll
    for (int tt = 0; tt < 9; ++tt) a[tt] = v0[tt * SLICE];
    #pragma unroll
    for (int tt = 0; tt < 9; ++tt) d[tt] = v1[tt * SLICE];
    #pragma unroll
    for (int tt = 0; tt < 9; ++tt) m[tt] = go[tt * SLICE];
    float sc0 = nrm[bb * 2], sh0 = nrm[16 + bb * 2];
    float sc1 = nrm[bb * 2 + 1], sh1 = nrm[16 + bb * 2 + 1];
    float k00 = Kc[o2 * 6 + 0], k01 = Kc[o2 * 6 + 1], k02 = Kc[o2 * 6 + 2];
    float k10 = Kc[o2 * 6 + 3], k11 = Kc[o2 * 6 + 4], k12 = Kc[o2 * 6 + 5];
    #pragma unroll
    for (int tt = 0; tt < 9; ++tt) { a[tt] = a[tt] * sc0 + sh0; d[tt] = d[tt] * sc1 + sh1; }
    float ls = 0.f, lq = 0.f;
    #pragma unroll
    for (int tt = 0; tt < 9; ++tt) {
        float pre = k01 * a[tt] + k11 * d[tt];
        if (tt > 0) pre += k00 * a[tt - 1] + k10 * d[tt - 1];
        if (tt < 8) pre += k02 * a[tt + 1] + k12 * d[tt + 1];
        float sig = 1.0f / (1.0f + expf(-pre));
        float g = sig * m[tt];
        go[tt * SLICE] = g;
        ls += g; lq += g * g;
    }
    __shared__ float ss[256], sq[256];
    ss[threadIdx.x] = ls; sq[threadIdx.x] = lq;
    __syncthreads();
    for (int ofs = 128; ofs > 0; ofs >>= 1) {
        if (threadIdx.x < ofs) { ss[threadIdx.x] += ss[threadIdx.x + ofs]; sq[threadIdx.x] += sq[threadIdx.x + ofs]; }
        __syncthreads();
    }
    if (threadIdx.x == 0) {
        int bc = bb * 2 + o2;
        atomicAdd(&s2[bc], ss[0]); atomicAdd(&s2[16 + bc], sq[0]);
    }
}

// ---------------- K7: final instance norm in place (float4) ----------------
__global__ void k_norm(float* __restrict__ out, const float* __restrict__ s2) {
    int i4 = blockIdx.x * 256 + threadIdx.x;    // grid = TOT/1024
    int bc = i4 / (CHW / 4);
    float m = s2[bc] * INV_M;
    float var = s2[16 + bc] * INV_M - m * m;
    float inv = rsqrtf(var + 1e-5f);
    float4 v = ((float4*)out)[i4];
    v.x = (v.x - m) * inv; v.y = (v.y - m) * inv;
    v.z = (v.z - m) * inv; v.w = (v.w - m) * inv;
    ((float4*)out)[i4] = v;
}

extern "C" void kernel_launch(void* const* d_in, const int* in_sizes, int n_in,
                              void* d_out, int out_size, void* d_ws, size_t ws_size,
                              hipStream_t stream) {
    const float* t  = (const float*)d_in[0];
    const int*   x  = (const int*)d_in[1];
    const int*   y  = (const int*)d_in[2];
    const int*   p  = (const int*)d_in[3];
    const int*   b  = (const int*)d_in[4];
    const float* conv1_w = (const float*)d_in[5];
    // d_in[6], d_in[7] (fc1_w, fc2_w): unused — attention is exactly uniform
    const float* dyn_w   = (const float*)d_in[8];
    const float* conv3_w = (const float*)d_in[9];
    float* out = (float*)d_out;
    int n = in_sizes[0];

    long availF = (long)(ws_size / sizeof(float));
    long need = (long)TOT + 2L * n + 1024;       // vox + rec + tail
    int useBuckets = (availF >= need);

    float* ws   = (float*)d_ws;
    float* vox  = ws;                                        // TOT
    int2*  rec  = (int2*)(ws + TOT);                         // n records
    float* tail = ws + TOT + (useBuckets ? 2L * n : 0);
    unsigned* gmax    = (unsigned*)tail;                     // +0   (8)
    float*    s1      = tail + 8;                            // +8   (32)
    float*    nrm     = tail + 40;                           // +40  (32)
    float*    Kc      = tail + 72;                           // +72  (12)
    float*    s2      = tail + 84;                           // +84  (32)
    int*      start   = (int*)(tail + 116);                  // +116 (12)
    unsigned* hist    = (unsigned*)(tail + 128);             // +128 (288)
    unsigned* segbase = (unsigned*)(tail + 416);             // +416 (288)
    unsigned* cursor  = (unsigned*)(tail + 704);             // +704 (288)

    hipMemsetAsync(tail, 0, 416 * sizeof(float), stream);    // gmax..hist zeroed

    k_bounds<<<1, 64, 0, stream>>>(b, start, n);
    k_tmax<<<2048, 256, 0, stream>>>(t, start, gmax);
    if (useBuckets) {
        k_hist<<<2048, 256, 0, stream>>>(t, y, gmax, start, hist);
        k_scan<<<1, 64, 0, stream>>>(start, hist, segbase, cursor);
        k_place<<<2048, 256, 0, stream>>>(t, x, y, p, gmax, start, cursor, rec);
        k_scat_b<<<dim3(9, 8, 4), 512, 0, stream>>>(rec, hist, segbase, vox);
    } else {
        k_scat<<<dim3(9, 8, 1), 1024, 0, stream>>>(t, x, y, p, gmax, start, vox);
    }
    k_mask<<<576, 256, 0, stream>>>(vox, out, s1);           // d_out holds mask
    k_prep<<<1, 64, 0, stream>>>(conv1_w, dyn_w, conv3_w, s1, nrm, Kc);
    k_g<<<1024, 256, 0, stream>>>(vox, out, nrm, Kc, s2);
    k_norm<<<TOT / 1024, 256, 0, stream>>>(out, s2);
}

// Round 7
// 216.214 us; speedup vs baseline: 3.7668x; 1.1102x over previous
//
#include <hip/hip_runtime.h>
#include <math.h>

#define TT 9
#define HH 128
#define WW 128
#define BB 8
#define SLICE (HH*WW)           // 16384
#define CHW (TT*SLICE)          // 147456
#define BCH (2*CHW)             // 294912
#define TOT (BB*BCH)            // 2359296
#define INV_M (1.0f/147456.0f)
#define NYG 16                  // y-groups of 8 rows
#define NBK (9*NYG)             // 144 buckets per batch

// ---------------- K0: batch bounds (b sorted) + data-independent Kc --------
__global__ void k_bounds(const int* __restrict__ b, int* __restrict__ start, int n,
                         const float* __restrict__ conv1_w, const float* __restrict__ dyn_w,
                         const float* __restrict__ conv3_w, float* __restrict__ Kc) {
    int tid = threadIdx.x;
    if (tid < 9) {
        if (tid == 0) start[0] = 0;
        else if (tid == 8) start[8] = n;
        else {
            int lo = 0, hi = n;
            while (lo < hi) { int mid = (lo + hi) >> 1; if (b[mid] < tid) lo = mid + 1; else hi = mid; }
            start[tid] = lo;
        }
    }
    if (tid >= 32 && tid < 44) {
        int q = tid - 32;             // Kc[o2*6 + c*3 + d]
        int d = q % 3, c = (q / 3) & 1, o2 = q / 6;
        float acc = 0.0f;
        for (int o = 0; o < 16; ++o) {
            float c3 = conv3_w[o2 * 16 + o];
            for (int i = 0; i < 16; ++i) {
                float wsum = 0.0f;
                for (int k = 0; k < 4; ++k) wsum += dyn_w[((k * 16 + o) * 16 + i) * 3 + d];
                acc += c3 * (0.25f * wsum) * conv1_w[i * 2 + c];
                // attention is exactly uniform: pooled mean of inorm output is 0
            }
        }
        Kc[q] = acc;
    }
}

// ---------------- K1: per-batch max of t -----------------------------------
__global__ void k_tmax(const float* __restrict__ t, const int* __restrict__ start,
                       unsigned* __restrict__ gmax) {
    __shared__ unsigned sm[256];
    int bi = blockIdx.x & 7;
    int cj = blockIdx.x >> 3;
    int nb = gridDim.x >> 3;
    int s = start[bi], e = start[bi + 1];
    int len = e - s;
    if (len <= 0) return;
    int per = (len + nb - 1) / nb;
    int lo = s + cj * per;
    int hi = lo + per < e ? lo + per : e;
    unsigned m = 0u;
    for (int i = lo + threadIdx.x; i < hi; i += 256) {
        unsigned tv = __float_as_uint(t[i]);   // t >= 0: uint order == float order
        if (tv > m) m = tv;
    }
    sm[threadIdx.x] = m;
    __syncthreads();
    for (int ofs = 128; ofs > 0; ofs >>= 1) {
        if (threadIdx.x < ofs && sm[threadIdx.x + ofs] > sm[threadIdx.x])
            sm[threadIdx.x] = sm[threadIdx.x + ofs];
        __syncthreads();
    }
    if (threadIdx.x == 0 && sm[0]) atomicMax(&gmax[bi], sm[0]);
}

// ---------------- K2a: histogram of (t-bin, y-group) per batch -------------
__global__ void __launch_bounds__(256) k_hist(
        const float* __restrict__ t, const int* __restrict__ y,
        const unsigned* __restrict__ gmax, const int* __restrict__ start,
        unsigned* __restrict__ hist) {
    __shared__ unsigned lh[NBK];
    int bi = blockIdx.x & 7, cj = blockIdx.x >> 3, nb = gridDim.x >> 3;
    int s = start[bi], e = start[bi + 1], len = e - s;
    if (threadIdx.x < NBK) lh[threadIdx.x] = 0u;
    __syncthreads();
    if (len > 0) {
        int per = (len + nb - 1) / nb;
        int lo = s + cj * per;
        int hi = lo + per < e ? lo + per : e;
        float tmax = __uint_as_float(gmax[bi]);
        #pragma unroll 4
        for (int i = lo + threadIdx.x; i < hi; i += 256) {
            float ts = t[i] / tmax * 9.0f;       // same op order as reference
            int i0 = (int)floorf(ts);
            if ((unsigned)i0 < 9u) atomicAdd(&lh[i0 * NYG + (y[i] >> 3)], 1u);
        }
    }
    __syncthreads();
    if (threadIdx.x < NBK) {
        unsigned c = lh[threadIdx.x];
        if (c) atomicAdd(&hist[bi * NBK + threadIdx.x], c);
    }
}

// ---------------- K2b: exclusive scan -> segment bases + working cursors ---
__global__ void k_scan(const int* __restrict__ start, const unsigned* __restrict__ hist,
                       unsigned* __restrict__ segbase, unsigned* __restrict__ cursor) {
    int b = threadIdx.x;
    if (b < 8) {
        unsigned base = (unsigned)start[b];
        for (int lb = 0; lb < NBK; ++lb) {
            segbase[b * NBK + lb] = base;
            cursor[b * NBK + lb] = base;
            base += hist[b * NBK + lb];
        }
    }
}

// ---------------- K2c: place records into bucket segments ------------------
__global__ void __launch_bounds__(256) k_place(
        const float* __restrict__ t, const int* __restrict__ x,
        const int* __restrict__ y, const int* __restrict__ p,
        const unsigned* __restrict__ gmax, const int* __restrict__ start,
        unsigned* __restrict__ cursor, int2* __restrict__ rec) {
    __shared__ unsigned lh[NBK];
    __shared__ unsigned lc[NBK];
    int bi = blockIdx.x & 7, cj = blockIdx.x >> 3, nb = gridDim.x >> 3;
    int s = start[bi], e = start[bi + 1], len = e - s;
    if (len <= 0) return;
    int per = (len + nb - 1) / nb;
    int lo = s + cj * per;
    int hi = lo + per < e ? lo + per : e;
    float tmax = __uint_as_float(gmax[bi]);
    for (int base = lo; base < hi; base += 2048) {
        if (threadIdx.x < NBK) lh[threadIdx.x] = 0u;
        __syncthreads();
        int lb[8]; float tsv[8]; int keyv[8];
        #pragma unroll
        for (int k = 0; k < 8; ++k) {
            int idx = base + (k << 8) + threadIdx.x;
            lb[k] = -1; tsv[k] = 0.f; keyv[k] = 0;
            if (idx < hi) {
                float ts = t[idx] / tmax * 9.0f;     // same op order as reference
                int yy = y[idx];
                int i0 = (int)floorf(ts);
                if ((unsigned)i0 < 9u) {
                    lb[k] = i0 * NYG + (yy >> 3);
                    tsv[k] = ts;
                    keyv[k] = x[idx] + (yy << 7) + (p[idx] << 14);
                }
            }
        }
        #pragma unroll
        for (int k = 0; k < 8; ++k)
            if (lb[k] >= 0) atomicAdd(&lh[lb[k]], 1u);
        __syncthreads();
        if (threadIdx.x < NBK) {
            unsigned c = lh[threadIdx.x];
            lc[threadIdx.x] = c ? atomicAdd(&cursor[bi * NBK + threadIdx.x], c) : 0u;
        }
        __syncthreads();
        #pragma unroll
        for (int k = 0; k < 8; ++k)
            if (lb[k] >= 0) {
                unsigned slot = atomicAdd(&lc[lb[k]], 1u);
                rec[slot] = make_int2(__float_as_int(tsv[k]), keyv[k]);
            }
        __syncthreads();
    }
}

// ---------------- K2d: bucketed scatter, direct vox write ------------------
// Block (tg, b, yg): owns vox[b][0..1][tg][yg*8..+8][*] = 8 KB in LDS.
// Reads bucket (b,tg,yg) with w0 = 1-(ts-tg) and bucket (b,tg-1,yg) with
// w1 = 1-(tg-ts): every record accepted, no filtering waste, no merge.
// key bits: [6:0]=x [13:7]=y [14]=p -> lds idx = p*1024 + (y&7)*128 + x
#define SCB(r, WEXPR)                                                       \
    {   float ts = __int_as_float((r).x);                                   \
        float w = (WEXPR);                                                  \
        int k = (r).y;                                                      \
        atomicAdd(&sl[(k & 1023) | ((k >> 4) & 1024)], w); }

__global__ void __launch_bounds__(256) k_scat_b(
        const int2* __restrict__ rec, const unsigned* __restrict__ hist,
        const unsigned* __restrict__ segbase, float* __restrict__ vox) {
    __shared__ float sl[2048];                   // 8 KiB
    int tg = blockIdx.x, bb = blockIdx.y, yg = blockIdx.z;
    for (int j = threadIdx.x; j < 2048; j += 256) sl[j] = 0.0f;
    __syncthreads();
    float ftg = (float)tg;
    {   // lower-bin deposits: records with i0 == tg; fl == ftg exactly
        int lb = bb * NBK + tg * NYG + yg;
        unsigned sA = segbase[lb], eA = sA + hist[lb];
        unsigned i = sA + threadIdx.x;
        for (; i + 7 * 256 < eA; i += 8 * 256) {
            int2 r0 = rec[i],            r1 = rec[i + 256];
            int2 r2 = rec[i + 2 * 256],  r3 = rec[i + 3 * 256];
            int2 r4 = rec[i + 4 * 256],  r5 = rec[i + 5 * 256];
            int2 r6 = rec[i + 6 * 256],  r7 = rec[i + 7 * 256];
            SCB(r0, 1.0f - (ts - ftg)) SCB(r1, 1.0f - (ts - ftg))
            SCB(r2, 1.0f - (ts - ftg)) SCB(r3, 1.0f - (ts - ftg))
            SCB(r4, 1.0f - (ts - ftg)) SCB(r5, 1.0f - (ts - ftg))
            SCB(r6, 1.0f - (ts - ftg)) SCB(r7, 1.0f - (ts - ftg))
        }
        for (; i < eA; i += 256) { int2 r = rec[i]; SCB(r, 1.0f - (ts - ftg)) }
    }
    if (tg > 0) {  // upper-bin deposits: records with i0 == tg-1, i1 == tg
        int lb = bb * NBK + (tg - 1) * NYG + yg;
        unsigned sB = segbase[lb], eB = sB + hist[lb];
        unsigned i = sB + threadIdx.x;
        for (; i + 7 * 256 < eB; i += 8 * 256) {
            int2 r0 = rec[i],            r1 = rec[i + 256];
            int2 r2 = rec[i + 2 * 256],  r3 = rec[i + 3 * 256];
            int2 r4 = rec[i + 4 * 256],  r5 = rec[i + 5 * 256];
            int2 r6 = rec[i + 6 * 256],  r7 = rec[i + 7 * 256];
            SCB(r0, 1.0f - (ftg - ts)) SCB(r1, 1.0f - (ftg - ts))
            SCB(r2, 1.0f - (ftg - ts)) SCB(r3, 1.0f - (ftg - ts))
            SCB(r4, 1.0f - (ftg - ts)) SCB(r5, 1.0f - (ftg - ts))
            SCB(r6, 1.0f - (ftg - ts)) SCB(r7, 1.0f - (ftg - ts))
        }
        for (; i < eB; i += 256) { int2 r = rec[i]; SCB(r, 1.0f - (ftg - ts)) }
    }
    __syncthreads();
    float* d0 = vox + (size_t)bb * BCH + (size_t)tg * SLICE + (yg << 10);
    ((float4*)d0)[threadIdx.x]         = ((float4*)sl)[threadIdx.x];        // p=0
    ((float4*)(d0 + CHW))[threadIdx.x] = ((float4*)(sl + 1024))[threadIdx.x]; // p=1
}

// ---------------- K2 fallback: unpacked 9x-rescan, direct vox --------------
__global__ void __launch_bounds__(1024, 4) k_scat(
        const float* __restrict__ t, const int* __restrict__ x,
        const int* __restrict__ y, const int* __restrict__ p,
        const unsigned* __restrict__ gmax, const int* __restrict__ start,
        float* __restrict__ vox) {
    __shared__ float sl[2 * SLICE];
    int tg = blockIdx.x, bb = blockIdx.y;
    int cs = start[bb], ce = start[bb + 1];
    for (int j = threadIdx.x; j < 2 * SLICE; j += 1024) sl[j] = 0.0f;
    __syncthreads();
    float tmax = __uint_as_float(gmax[bb]);
    float ftg = (float)tg;
    for (int i = cs + threadIdx.x; i < ce; i += 1024) {
        float ts = t[i] / tmax * 9.0f;
        float fl = floorf(ts);
        int i0 = (int)fl;
        bool h0 = (i0 == tg), h1 = (i0 + 1 == tg);
        if (h0 | h1) {
            float w = h0 ? (1.0f - (ts - fl)) : (1.0f - (ftg - ts));
            int hw = x[i] + (y[i] << 7) + (p[i] << 14);
            atomicAdd(&sl[hw], w);
        }
    }
    __syncthreads();
    float* dst = vox + (size_t)bb * BCH + (size_t)tg * SLICE;
    for (int j = threadIdx.x; j < SLICE; j += 1024) {
        dst[j]       = sl[j];
        dst[CHW + j] = sl[SLICE + j];
    }
}

// ---------------- K4: time-corr mask + fused inorm stats -------------------
#define STRIP 32
__global__ void k_mask(const float* __restrict__ vox, float* __restrict__ mask,
                       float* __restrict__ s1) {
    __shared__ unsigned char sbx[36 * 128];
    __shared__ unsigned char sar[34 * 128];
    __shared__ float red[256], red2[256];
    int bid = blockIdx.x;                  // 576 = 8*2*9*4
    int strip = bid & 3;
    int t = (bid >> 2) % 9;
    int c = (bid / 36) & 1;
    int bb = bid / 72;
    long off = (long)bb * BCH + (long)c * CHW;
    const float* vt = vox + off + (long)t * SLICE;
    int tn = (t + 1 < 9) ? t + 1 : 8;      // replication pad in T
    const float* vn = vox + off + (long)tn * SLICE;
    int y0 = strip * STRIP;
    float s_acc = 0.f, q_acc = 0.f;
    for (int j = threadIdx.x; j < 36 * 128; j += 256) {
        int r = j >> 7, xx = j & 127;
        int gy = y0 - 2 + r;
        float v = 0.f;
        bool in = (unsigned)gy < 128u;
        if (in) v = vt[(gy << 7) + xx];
        sbx[j] = (in && v > 0.0f) ? 1 : 0;
        if (r >= 2 && r < 34) { s_acc += v; q_acc += v * v; }  // owned rows
    }
    __syncthreads();
    for (int j = threadIdx.x; j < 34 * 128; j += 256) {
        int ra = j >> 7, xx = j & 127;
        int gy = y0 - 1 + ra;
        unsigned char v = 0;
        if ((unsigned)gy < 128u) {
            int s = 0;
            for (int rs = ra; rs <= ra + 2; ++rs)
                for (int dx = -1; dx <= 1; ++dx) {
                    int x2 = xx + dx; if ((unsigned)x2 >= 128u) continue;
                    s += sbx[(rs << 7) + x2];
                }
            // prev*bxn > 4/9  <=>  bxn==1 && boxsum >= 5  (exact integer form)
            v = (vn[(gy << 7) + xx] > 0.0f && s >= 5) ? 1 : 0;
        }
        sar[j] = v;
    }
    __syncthreads();
    float* mt = mask + off + (long)t * SLICE;
    for (int j = threadIdx.x; j < STRIP * 128; j += 256) {
        int q = j >> 7, xx = j & 127;
        int s = 0;
        for (int ra = q; ra <= q + 2; ++ra)
            for (int dx = -1; dx <= 1; ++dx) {
                int x2 = xx + dx; if ((unsigned)x2 >= 128u) continue;
                s += sar[(ra << 7) + x2];
            }
        mt[((y0 + q) << 7) + xx] = (float)s / 9.0f;
    }
    red[threadIdx.x] = s_acc; red2[threadIdx.x] = q_acc;
    __syncthreads();
    for (int ofs = 128; ofs > 0; ofs >>= 1) {
        if (threadIdx.x < ofs) { red[threadIdx.x] += red[threadIdx.x + ofs]; red2[threadIdx.x] += red2[threadIdx.x + ofs]; }
        __syncthreads();
    }
    if (threadIdx.x == 0) {
        int bc = bb * 2 + c;
        atomicAdd(&s1[bc], red[0]); atomicAdd(&s1[16 + bc], red2[0]);
    }
}

// ---------------- K6: whole t-column per thread (nrm folded in) ------------
__global__ void __launch_bounds__(256) k_g(
        const float* __restrict__ vox, float* __restrict__ gm,
        const float* __restrict__ s1, const float* __restrict__ Kc,
        float* __restrict__ s2) {
    __shared__ float snrm[32];
    if (threadIdx.x < 16) {
        float mm = s1[threadIdx.x] * INV_M;
        float var = s1[16 + threadIdx.x] * INV_M - mm * mm;
        float inv = rsqrtf(var + 1e-5f);
        snrm[threadIdx.x] = inv;
        snrm[16 + threadIdx.x] = -mm * inv;
    }
    __syncthreads();
    int idx = blockIdx.x * 256 + threadIdx.x;   // (b,o2,hw): 8*2*16384 threads
    int hw = idx & (SLICE - 1);
    int o2 = (idx >> 14) & 1;
    int bb = idx >> 15;
    const float* v0 = vox + (size_t)bb * BCH + hw;       // c=0 column
    const float* v1 = v0 + CHW;                          // c=1 column
    float* go = gm + (size_t)bb * BCH + (size_t)o2 * CHW + hw;
    float a[9], d[9], m[9];
    #pragma unroll
    for (int tt = 0; tt < 9; ++tt) a[tt] = v0[tt * SLICE];
    #pragma unroll
    for (int tt = 0; tt < 9; ++tt) d[tt] = v1[tt * SLICE];
    #pragma unroll
    for (int tt = 0; tt < 9; ++tt) m[tt] = go[tt * SLICE];
    float sc0 = snrm[bb * 2], sh0 = snrm[16 + bb * 2];
    float sc1 = snrm[bb * 2 + 1], sh1 = snrm[16 + bb * 2 + 1];
    float k00 = Kc[o2 * 6 + 0], k01 = Kc[o2 * 6 + 1], k02 = Kc[o2 * 6 + 2];
    float k10 = Kc[o2 * 6 + 3], k11 = Kc[o2 * 6 + 4], k12 = Kc[o2 * 6 + 5];
    #pragma unroll
    for (int tt = 0; tt < 9; ++tt) { a[tt] = a[tt] * sc0 + sh0; d[tt] = d[tt] * sc1 + sh1; }
    float ls = 0.f, lq = 0.f;
    #pragma unroll
    for (int tt = 0; tt < 9; ++tt) {
        float pre = k01 * a[tt] + k11 * d[tt];
        if (tt > 0) pre += k00 * a[tt - 1] + k10 * d[tt - 1];
        if (tt < 8) pre += k02 * a[tt + 1] + k12 * d[tt + 1];
        float sig = 1.0f / (1.0f + expf(-pre));
        float g = sig * m[tt];
        go[tt * SLICE] = g;
        ls += g; lq += g * g;
    }
    __shared__ float ss[256], sq[256];
    ss[threadIdx.x] = ls; sq[threadIdx.x] = lq;
    __syncthreads();
    for (int ofs = 128; ofs > 0; ofs >>= 1) {
        if (threadIdx.x < ofs) { ss[threadIdx.x] += ss[threadIdx.x + ofs]; sq[threadIdx.x] += sq[threadIdx.x + ofs]; }
        __syncthreads();
    }
    if (threadIdx.x == 0) {
        int bc = bb * 2 + o2;
        atomicAdd(&s2[bc], ss[0]); atomicAdd(&s2[16 + bc], sq[0]);
    }
}

// ---------------- K7: final instance norm in place (float4) ----------------
__global__ void k_norm(float* __restrict__ out, const float* __restrict__ s2) {
    int i4 = blockIdx.x * 256 + threadIdx.x;    // grid = TOT/1024
    int bc = i4 / (CHW / 4);
    float m = s2[bc] * INV_M;
    float var = s2[16 + bc] * INV_M - m * m;
    float inv = rsqrtf(var + 1e-5f);
    float4 v = ((float4*)out)[i4];
    v.x = (v.x - m) * inv; v.y = (v.y - m) * inv;
    v.z = (v.z - m) * inv; v.w = (v.w - m) * inv;
    ((float4*)out)[i4] = v;
}

extern "C" void kernel_launch(void* const* d_in, const int* in_sizes, int n_in,
                              void* d_out, int out_size, void* d_ws, size_t ws_size,
                              hipStream_t stream) {
    const float* t  = (const float*)d_in[0];
    const int*   x  = (const int*)d_in[1];
    const int*   y  = (const int*)d_in[2];
    const int*   p  = (const int*)d_in[3];
    const int*   b  = (const int*)d_in[4];
    const float* conv1_w = (const float*)d_in[5];
    // d_in[6], d_in[7] (fc1_w, fc2_w): unused — attention is exactly uniform
    const float* dyn_w   = (const float*)d_in[8];
    const float* conv3_w = (const float*)d_in[9];
    float* out = (float*)d_out;
    int n = in_sizes[0];

    long availF = (long)(ws_size / sizeof(float));
    long need = (long)TOT + 2L * n + 8192;       // vox + rec + tail
    int useBuckets = (availF >= need);

    float* ws   = (float*)d_ws;
    float* vox  = ws;                                        // TOT
    int2*  rec  = (int2*)(ws + TOT);                         // n records
    float* tail = ws + TOT + (useBuckets ? 2L * n : 0);
    // zeroed region: gmax(8) s1(32) s2(32) hist(1152) = 1224
    unsigned* gmax    = (unsigned*)tail;                     // +0
    float*    s1      = tail + 8;                            // +8
    float*    s2      = tail + 40;                           // +40
    unsigned* hist    = (unsigned*)(tail + 72);              // +72  (1152)
    // non-zeroed:
    float*    Kc      = tail + 1224;                         // +1224 (12)
    int*      start   = (int*)(tail + 1236);                 // +1236 (12)
    unsigned* segbase = (unsigned*)(tail + 1248);            // +1248 (1152)
    unsigned* cursor  = (unsigned*)(tail + 2400);            // +2400 (1152)

    hipMemsetAsync(tail, 0, 1224 * sizeof(float), stream);

    k_bounds<<<1, 64, 0, stream>>>(b, start, n, conv1_w, dyn_w, conv3_w, Kc);
    k_tmax<<<2048, 256, 0, stream>>>(t, start, gmax);
    if (useBuckets) {
        k_hist<<<2048, 256, 0, stream>>>(t, y, gmax, start, hist);
        k_scan<<<1, 64, 0, stream>>>(start, hist, segbase, cursor);
        k_place<<<2048, 256, 0, stream>>>(t, x, y, p, gmax, start, cursor, rec);
        k_scat_b<<<dim3(9, 8, NYG), 256, 0, stream>>>(rec, hist, segbase, vox);
    } else {
        k_scat<<<dim3(9, 8, 1), 1024, 0, stream>>>(t, x, y, p, gmax, start, vox);
    }
    k_mask<<<576, 256, 0, stream>>>(vox, out, s1);           // d_out holds mask
    k_g<<<1024, 256, 0, stream>>>(vox, out, s1, Kc, s2);
    k_norm<<<TOT / 1024, 256, 0, stream>>>(out, s2);
}

// Round 8
// 190.764 us; speedup vs baseline: 4.2693x; 1.1334x over previous
//
#include <hip/hip_runtime.h>
#include <math.h>

#define TT 9
#define HH 128
#define WW 128
#define BB 8
#define SLICE (HH*WW)           // 16384
#define CHW (TT*SLICE)          // 147456
#define BCH (2*CHW)             // 294912
#define TOT (BB*BCH)            // 2359296
#define INV_M (1.0f/147456.0f)
#define NYG 16                  // y-groups of 8 rows
#define NBK (9*NYG)             // 144 buckets per batch

// ---------------- K0: batch bounds (b sorted) + data-independent Kc --------
__global__ void k_bounds(const int* __restrict__ b, int* __restrict__ start, int n,
                         const float* __restrict__ conv1_w, const float* __restrict__ dyn_w,
                         const float* __restrict__ conv3_w, float* __restrict__ Kc) {
    int tid = threadIdx.x;
    if (tid < 9) {
        if (tid == 0) start[0] = 0;
        else if (tid == 8) start[8] = n;
        else {
            int lo = 0, hi = n;
            while (lo < hi) { int mid = (lo + hi) >> 1; if (b[mid] < tid) lo = mid + 1; else hi = mid; }
            start[tid] = lo;
        }
    }
    if (tid >= 32 && tid < 44) {
        int q = tid - 32;             // Kc[o2*6 + c*3 + d]
        int d = q % 3, c = (q / 3) & 1, o2 = q / 6;
        float acc = 0.0f;
        for (int o = 0; o < 16; ++o) {
            float c3 = conv3_w[o2 * 16 + o];
            for (int i = 0; i < 16; ++i) {
                float wsum = 0.0f;
                for (int k = 0; k < 4; ++k) wsum += dyn_w[((k * 16 + o) * 16 + i) * 3 + d];
                acc += c3 * (0.25f * wsum) * conv1_w[i * 2 + c];
                // attention is exactly uniform: pooled mean of inorm output is 0
            }
        }
        Kc[q] = acc;
    }
}

// ---------------- K1: per-batch max of t (float4 vectorized) ---------------
__global__ void __launch_bounds__(256) k_tmax(
        const float* __restrict__ t, const int* __restrict__ start,
        unsigned* __restrict__ gmax) {
    __shared__ unsigned sm[256];
    int bi = blockIdx.x & 7, cj = blockIdx.x >> 3, nb = gridDim.x >> 3;
    int s = start[bi], e = start[bi + 1];
    unsigned m = 0u;
    if (e > s) {
        int a = (s + 3) & ~3; if (a > e) a = e;
        int z = e & ~3;       if (z < a) z = a;
        if (cj == 0) {       // head/tail scalars (<=3 each)
            int i = s + (int)threadIdx.x;
            if (i < a) { unsigned v = __float_as_uint(t[i]); if (v > m) m = v; }
            i = z + (int)threadIdx.x;
            if (i < e) { unsigned v = __float_as_uint(t[i]); if (v > m) m = v; }
        }
        long nq = (long)(z - a) >> 2;
        long per = (nq + nb - 1) / nb;
        long q0 = (long)cj * per; if (q0 > nq) q0 = nq;
        long q1 = q0 + per;       if (q1 > nq) q1 = nq;
        const float4* tp = (const float4*)(t + a);
        long i = q0 + threadIdx.x;
        for (; i + 256 < q1; i += 512) {
            float4 u = tp[i], v = tp[i + 256];
            float mu = fmaxf(fmaxf(u.x, u.y), fmaxf(u.z, u.w));
            float mv = fmaxf(fmaxf(v.x, v.y), fmaxf(v.z, v.w));
            unsigned c = __float_as_uint(fmaxf(mu, mv));   // t>=0: float==uint order
            if (c > m) m = c;
        }
        for (; i < q1; i += 256) {
            float4 u = tp[i];
            unsigned c = __float_as_uint(fmaxf(fmaxf(u.x, u.y), fmaxf(u.z, u.w)));
            if (c > m) m = c;
        }
    }
    sm[threadIdx.x] = m;
    __syncthreads();
    for (int ofs = 128; ofs > 0; ofs >>= 1) {
        if (threadIdx.x < ofs && sm[threadIdx.x + ofs] > sm[threadIdx.x])
            sm[threadIdx.x] = sm[threadIdx.x + ofs];
        __syncthreads();
    }
    if (threadIdx.x == 0 && sm[0]) atomicMax(&gmax[bi], sm[0]);
}

// ---------------- K2a: histogram of (t-bin, y-group), float4/int4 ----------
__global__ void __launch_bounds__(256) k_hist(
        const float* __restrict__ t, const int* __restrict__ y,
        const unsigned* __restrict__ gmax, const int* __restrict__ start,
        unsigned* __restrict__ hist) {
    __shared__ unsigned lh[NBK];
    int bi = blockIdx.x & 7, cj = blockIdx.x >> 3, nb = gridDim.x >> 3;
    int s = start[bi], e = start[bi + 1];
    for (int j = threadIdx.x; j < NBK; j += 256) lh[j] = 0u;
    __syncthreads();
    if (e > s) {
        float tmax = __uint_as_float(gmax[bi]);
        int a = (s + 3) & ~3; if (a > e) a = e;
        int z = e & ~3;       if (z < a) z = a;
        if (cj == 0) {
            int i = s + (int)threadIdx.x;
            if (i < a) { float ts = t[i] / tmax * 9.0f; int i0 = (int)floorf(ts);
                         if ((unsigned)i0 < 9u) atomicAdd(&lh[i0 * NYG + (y[i] >> 3)], 1u); }
            i = z + (int)threadIdx.x;
            if (i < e) { float ts = t[i] / tmax * 9.0f; int i0 = (int)floorf(ts);
                         if ((unsigned)i0 < 9u) atomicAdd(&lh[i0 * NYG + (y[i] >> 3)], 1u); }
        }
        long nq = (long)(z - a) >> 2;
        long per = (nq + nb - 1) / nb;
        long q0 = (long)cj * per; if (q0 > nq) q0 = nq;
        long q1 = q0 + per;       if (q1 > nq) q1 = nq;
        const float4* tp = (const float4*)(t + a);
        const int4*   yp = (const int4*)(y + a);
        for (long i = q0 + threadIdx.x; i < q1; i += 256) {
            float4 tv = tp[i]; int4 yv = yp[i];
            float tq[4] = {tv.x, tv.y, tv.z, tv.w};
            int   yq[4] = {yv.x, yv.y, yv.z, yv.w};
            #pragma unroll
            for (int k = 0; k < 4; ++k) {
                float ts = tq[k] / tmax * 9.0f;      // same op order as reference
                int i0 = (int)floorf(ts);
                if ((unsigned)i0 < 9u) atomicAdd(&lh[i0 * NYG + (yq[k] >> 3)], 1u);
            }
        }
    }
    __syncthreads();
    if (threadIdx.x < NBK) {
        unsigned c = lh[threadIdx.x];
        if (c) atomicAdd(&hist[bi * NBK + threadIdx.x], c);
    }
}

// ---------------- K2b: scan in LDS -> segment bases + cursors --------------
__global__ void __launch_bounds__(1024) k_scan(
        const int* __restrict__ start, const unsigned* __restrict__ hist,
        unsigned* __restrict__ segbase, unsigned* __restrict__ cursor) {
    __shared__ unsigned h[8 * NBK];
    for (int j = threadIdx.x; j < 8 * NBK; j += 1024) h[j] = hist[j];
    __syncthreads();
    if (threadIdx.x < 8) {
        int b = threadIdx.x;
        unsigned base = (unsigned)start[b];
        for (int lb = 0; lb < NBK; ++lb) {
            unsigned c = h[b * NBK + lb];
            h[b * NBK + lb] = base;
            base += c;
        }
    }
    __syncthreads();
    for (int j = threadIdx.x; j < 8 * NBK; j += 1024) {
        unsigned v = h[j]; segbase[j] = v; cursor[j] = v;
    }
}

// ---------------- K2c: place records (vectorized, 8 loads in flight) -------
__global__ void __launch_bounds__(256) k_place(
        const float* __restrict__ t, const int* __restrict__ x,
        const int* __restrict__ y, const int* __restrict__ p,
        const unsigned* __restrict__ gmax, const int* __restrict__ start,
        unsigned* __restrict__ cursor, int2* __restrict__ rec) {
    __shared__ unsigned lh[NBK], lc[NBK];
    int bi = blockIdx.x & 7, cj = blockIdx.x >> 3, nb = gridDim.x >> 3;
    int s = start[bi], e = start[bi + 1];
    if (e <= s) return;
    float tmax = __uint_as_float(gmax[bi]);
    int a = (s + 3) & ~3; if (a > e) a = e;
    int z = e & ~3;       if (z < a) z = a;
    long nq = (long)(z - a) >> 2;
    long per = (nq + nb - 1) / nb;
    long q0 = (long)cj * per; if (q0 > nq) q0 = nq;
    long q1 = q0 + per;       if (q1 > nq) q1 = nq;
    const float4* tp = (const float4*)(t + a);
    const int4*   xp = (const int4*)(x + a);
    const int4*   yp = (const int4*)(y + a);
    const int4*   pp = (const int4*)(p + a);
    for (long base = q0; base < q1; base += 512) {
        for (int j = threadIdx.x; j < NBK; j += 256) lh[j] = 0u;
        __syncthreads();
        int lb[8]; float tsv[8]; int keyv[8];
        #pragma unroll
        for (int h = 0; h < 2; ++h) {
            long qi = base + h * 256 + threadIdx.x;
            #pragma unroll
            for (int k = 0; k < 4; ++k) lb[h * 4 + k] = -1;
            if (qi < q1) {
                float4 tv = tp[qi]; int4 xv = xp[qi]; int4 yv = yp[qi]; int4 pv = pp[qi];
                float tq[4] = {tv.x, tv.y, tv.z, tv.w};
                int   xq[4] = {xv.x, xv.y, xv.z, xv.w};
                int   yq[4] = {yv.x, yv.y, yv.z, yv.w};
                int   pq[4] = {pv.x, pv.y, pv.z, pv.w};
                #pragma unroll
                for (int k = 0; k < 4; ++k) {
                    float ts = tq[k] / tmax * 9.0f;  // same op order as reference
                    int i0 = (int)floorf(ts);
                    if ((unsigned)i0 < 9u) {
                        lb[h * 4 + k] = i0 * NYG + (yq[k] >> 3);
                        tsv[h * 4 + k] = ts;
                        keyv[h * 4 + k] = xq[k] + (yq[k] << 7) + (pq[k] << 14);
                    }
                }
            }
        }
        #pragma unroll
        for (int k = 0; k < 8; ++k) if (lb[k] >= 0) atomicAdd(&lh[lb[k]], 1u);
        __syncthreads();
        for (int j = threadIdx.x; j < NBK; j += 256) {
            unsigned c = lh[j];
            lc[j] = c ? atomicAdd(&cursor[bi * NBK + j], c) : 0u;
        }
        __syncthreads();
        #pragma unroll
        for (int k = 0; k < 8; ++k)
            if (lb[k] >= 0) {
                unsigned slot = atomicAdd(&lc[lb[k]], 1u);
                rec[slot] = make_int2(__float_as_int(tsv[k]), keyv[k]);
            }
        __syncthreads();
    }
    if (cj == 0) {   // head/tail scalars (<=3 each), direct cursor reserve
        int i = -1;
        if ((int)threadIdx.x < a - s) i = s + threadIdx.x;
        else if (threadIdx.x >= 64 && (int)(threadIdx.x - 64) < e - z) i = z + (threadIdx.x - 64);
        if (i >= 0) {
            float ts = t[i] / tmax * 9.0f;
            int i0 = (int)floorf(ts);
            if ((unsigned)i0 < 9u) {
                int lbx = i0 * NYG + (y[i] >> 3);
                unsigned slot = atomicAdd(&cursor[bi * NBK + lbx], 1u);
                rec[slot] = make_int2(__float_as_int(ts), x[i] + (y[i] << 7) + (p[i] << 14));
            }
        }
    }
}

// ---------------- K2d: bucketed scatter, int4 record loads -----------------
// Block (tg, b, yg): owns vox[b][0..1][tg][yg*8..+8][*] = 8 KB LDS.
// weight = 1 - sgn*(ts - ftg): sgn=+1 -> 1-(ts-fl) [i0==tg, fl==ftg exactly];
// sgn=-1 -> 1+(ts-ftg) == 1-(ftg-ts) bit-exact (negation is exact).
// key bits: [6:0]=x [13:7]=y [14]=p -> lds idx = p*1024 + (y&7)*128 + x
__device__ __forceinline__ void scat_stream(
        const int2* __restrict__ rec, unsigned s, unsigned e,
        float ftg, float sgn, float* __restrict__ sl) {
    unsigned a = (s + 1) & ~1u;
    unsigned z = e & ~1u; if (z < a) z = a;
    if (threadIdx.x == 0 && s < a && s < e) {
        int2 r = rec[s]; float ts = __int_as_float(r.x);
        atomicAdd(&sl[(r.y & 1023) | ((r.y >> 4) & 1024)], 1.0f - sgn * (ts - ftg));
    }
    if (threadIdx.x == 1 && z < e) {
        int2 r = rec[z]; float ts = __int_as_float(r.x);
        atomicAdd(&sl[(r.y & 1023) | ((r.y >> 4) & 1024)], 1.0f - sgn * (ts - ftg));
    }
    int n2 = (int)((z - a) >> 1);
    const int4* rp = (const int4*)(rec + a);
#define B2(q) { float ts0 = __int_as_float(q.x), ts1 = __int_as_float(q.z);          \
    atomicAdd(&sl[(q.y & 1023) | ((q.y >> 4) & 1024)], 1.0f - sgn * (ts0 - ftg));    \
    atomicAdd(&sl[(q.w & 1023) | ((q.w >> 4) & 1024)], 1.0f - sgn * (ts1 - ftg)); }
    int i = threadIdx.x;
    for (; i + 3 * 256 < n2; i += 4 * 256) {
        int4 q0 = rp[i], q1 = rp[i + 256], q2 = rp[i + 512], q3 = rp[i + 768];
        B2(q0) B2(q1) B2(q2) B2(q3)
    }
    for (; i < n2; i += 256) { int4 q = rp[i]; B2(q) }
#undef B2
}

__global__ void __launch_bounds__(256) k_scat_b(
        const int2* __restrict__ rec, const unsigned* __restrict__ hist,
        const unsigned* __restrict__ segbase, float* __restrict__ vox) {
    __shared__ float sl[2048];                   // 8 KiB
    int tg = blockIdx.x, bb = blockIdx.y, yg = blockIdx.z;
    for (int j = threadIdx.x; j < 2048; j += 256) sl[j] = 0.0f;
    __syncthreads();
    float ftg = (float)tg;
    {   // lower-bin deposits: bucket (b, tg, yg)
        int lb = bb * NBK + tg * NYG + yg;
        unsigned sA = segbase[lb];
        scat_stream(rec, sA, sA + hist[lb], ftg, 1.0f, sl);
    }
    if (tg > 0) {  // upper-bin deposits: bucket (b, tg-1, yg)
        int lb = bb * NBK + (tg - 1) * NYG + yg;
        unsigned sB = segbase[lb];
        scat_stream(rec, sB, sB + hist[lb], ftg, -1.0f, sl);
    }
    __syncthreads();
    float* d0 = vox + (size_t)bb * BCH + (size_t)tg * SLICE + (yg << 10);
    ((float4*)d0)[threadIdx.x]           = ((float4*)sl)[threadIdx.x];          // p=0
    ((float4*)(d0 + CHW))[threadIdx.x]   = ((float4*)(sl + 1024))[threadIdx.x]; // p=1
}

// ---------------- K2 fallback: unpacked 9x-rescan, direct vox --------------
__global__ void __launch_bounds__(1024, 4) k_scat(
        const float* __restrict__ t, const int* __restrict__ x,
        const int* __restrict__ y, const int* __restrict__ p,
        const unsigned* __restrict__ gmax, const int* __restrict__ start,
        float* __restrict__ vox) {
    __shared__ float sl[2 * SLICE];
    int tg = blockIdx.x, bb = blockIdx.y;
    int cs = start[bb], ce = start[bb + 1];
    for (int j = threadIdx.x; j < 2 * SLICE; j += 1024) sl[j] = 0.0f;
    __syncthreads();
    float tmax = __uint_as_float(gmax[bb]);
    float ftg = (float)tg;
    for (int i = cs + threadIdx.x; i < ce; i += 1024) {
        float ts = t[i] / tmax * 9.0f;
        float fl = floorf(ts);
        int i0 = (int)fl;
        bool h0 = (i0 == tg), h1 = (i0 + 1 == tg);
        if (h0 | h1) {
            float w = h0 ? (1.0f - (ts - fl)) : (1.0f - (ftg - ts));
            int hw = x[i] + (y[i] << 7) + (p[i] << 14);
            atomicAdd(&sl[hw], w);
        }
    }
    __syncthreads();
    float* dst = vox + (size_t)bb * BCH + (size_t)tg * SLICE;
    for (int j = threadIdx.x; j < SLICE; j += 1024) {
        dst[j]       = sl[j];
        dst[CHW + j] = sl[SLICE + j];
    }
}

// ---------------- K4: time-corr mask + fused inorm stats -------------------
#define STRIP 32
__global__ void k_mask(const float* __restrict__ vox, float* __restrict__ mask,
                       float* __restrict__ s1) {
    __shared__ unsigned char sbx[36 * 128];
    __shared__ unsigned char sar[34 * 128];
    __shared__ float red[256], red2[256];
    int bid = blockIdx.x;                  // 576 = 8*2*9*4
    int strip = bid & 3;
    int t = (bid >> 2) % 9;
    int c = (bid / 36) & 1;
    int bb = bid / 72;
    long off = (long)bb * BCH + (long)c * CHW;
    const float* vt = vox + off + (long)t * SLICE;
    int tn = (t + 1 < 9) ? t + 1 : 8;      // replication pad in T
    const float* vn = vox + off + (long)tn * SLICE;
    int y0 = strip * STRIP;
    float s_acc = 0.f, q_acc = 0.f;
    for (int j = threadIdx.x; j < 36 * 128; j += 256) {
        int r = j >> 7, xx = j & 127;
        int gy = y0 - 2 + r;
        float v = 0.f;
        bool in = (unsigned)gy < 128u;
        if (in) v = vt[(gy << 7) + xx];
        sbx[j] = (in && v > 0.0f) ? 1 : 0;
        if (r >= 2 && r < 34) { s_acc += v; q_acc += v * v; }  // owned rows
    }
    __syncthreads();
    for (int j = threadIdx.x; j < 34 * 128; j += 256) {
        int ra = j >> 7, xx = j & 127;
        int gy = y0 - 1 + ra;
        unsigned char v = 0;
        if ((unsigned)gy < 128u) {
            int s = 0;
            for (int rs = ra; rs <= ra + 2; ++rs)
                for (int dx = -1; dx <= 1; ++dx) {
                    int x2 = xx + dx; if ((unsigned)x2 >= 128u) continue;
                    s += sbx[(rs << 7) + x2];
                }
            // prev*bxn > 4/9  <=>  bxn==1 && boxsum >= 5  (exact integer form)
            v = (vn[(gy << 7) + xx] > 0.0f && s >= 5) ? 1 : 0;
        }
        sar[j] = v;
    }
    __syncthreads();
    float* mt = mask + off + (long)t * SLICE;
    for (int j = threadIdx.x; j < STRIP * 128; j += 256) {
        int q = j >> 7, xx = j & 127;
        int s = 0;
        for (int ra = q; ra <= q + 2; ++ra)
            for (int dx = -1; dx <= 1; ++dx) {
                int x2 = xx + dx; if ((unsigned)x2 >= 128u) continue;
                s += sar[(ra << 7) + x2];
            }
        mt[((y0 + q) << 7) + xx] = (float)s / 9.0f;
    }
    red[threadIdx.x] = s_acc; red2[threadIdx.x] = q_acc;
    __syncthreads();
    for (int ofs = 128; ofs > 0; ofs >>= 1) {
        if (threadIdx.x < ofs) { red[threadIdx.x] += red[threadIdx.x + ofs]; red2[threadIdx.x] += red2[threadIdx.x + ofs]; }
        __syncthreads();
    }
    if (threadIdx.x == 0) {
        int bc = bb * 2 + c;
        atomicAdd(&s1[bc], red[0]); atomicAdd(&s1[16 + bc], red2[0]);
    }
}

// ---------------- K6: whole t-column per thread (nrm folded in) ------------
__global__ void __launch_bounds__(256) k_g(
        const float* __restrict__ vox, float* __restrict__ gm,
        const float* __restrict__ s1, const float* __restrict__ Kc,
        float* __restrict__ s2) {
    __shared__ float snrm[32];
    if (threadIdx.x < 16) {
        float mm = s1[threadIdx.x] * INV_M;
        float var = s1[16 + threadIdx.x] * INV_M - mm * mm;
        float inv = rsqrtf(var + 1e-5f);
        snrm[threadIdx.x] = inv;
        snrm[16 + threadIdx.x] = -mm * inv;
    }
    __syncthreads();
    int idx = blockIdx.x * 256 + threadIdx.x;   // (b,o2,hw): 8*2*16384 threads
    int hw = idx & (SLICE - 1);
    int o2 = (idx >> 14) & 1;
    int bb = idx >> 15;
    const float* v0 = vox + (size_t)bb * BCH + hw;       // c=0 column
    const float* v1 = v0 + CHW;                          // c=1 column
    float* go = gm + (size_t)bb * BCH + (size_t)o2 * CHW + hw;
    float a[9], d[9], m[9];
    #pragma unroll
    for (int tt = 0; tt < 9; ++tt) a[tt] = v0[tt * SLICE];
    #pragma unroll
    for (int tt = 0; tt < 9; ++tt) d[tt] = v1[tt * SLICE];
    #pragma unroll
    for (int tt = 0; tt < 9; ++tt) m[tt] = go[tt * SLICE];
    float sc0 = snrm[bb * 2], sh0 = snrm[16 + bb * 2];
    float sc1 = snrm[bb * 2 + 1], sh1 = snrm[16 + bb * 2 + 1];
    float k00 = Kc[o2 * 6 + 0], k01 = Kc[o2 * 6 + 1], k02 = Kc[o2 * 6 + 2];
    float k10 = Kc[o2 * 6 + 3], k11 = Kc[o2 * 6 + 4], k12 = Kc[o2 * 6 + 5];
    #pragma unroll
    for (int tt = 0; tt < 9; ++tt) { a[tt] = a[tt] * sc0 + sh0; d[tt] = d[tt] * sc1 + sh1; }
    float ls = 0.f, lq = 0.f;
    #pragma unroll
    for (int tt = 0; tt < 9; ++tt) {
        float pre = k01 * a[tt] + k11 * d[tt];
        if (tt > 0) pre += k00 * a[tt - 1] + k10 * d[tt - 1];
        if (tt < 8) pre += k02 * a[tt + 1] + k12 * d[tt + 1];
        float sig = 1.0f / (1.0f + expf(-pre));
        float g = sig * m[tt];
        go[tt * SLICE] = g;
        ls += g; lq += g * g;
    }
    __shared__ float ss[256], sq[256];
    ss[threadIdx.x] = ls; sq[threadIdx.x] = lq;
    __syncthreads();
    for (int ofs = 128; ofs > 0; ofs >>= 1) {
        if (threadIdx.x < ofs) { ss[threadIdx.x] += ss[threadIdx.x + ofs]; sq[threadIdx.x] += sq[threadIdx.x + ofs]; }
        __syncthreads();
    }
    if (threadIdx.x == 0) {
        int bc = bb * 2 + o2;
        atomicAdd(&s2[bc], ss[0]); atomicAdd(&s2[16 + bc], sq[0]);
    }
}

// ---------------- K7: final instance norm in place (float4) ----------------
__global__ void k_norm(float* __restrict__ out, const float* __restrict__ s2) {
    int i4 = blockIdx.x * 256 + threadIdx.x;    // grid = TOT/1024
    int bc = i4 / (CHW / 4);
    float m = s2[bc] * INV_M;
    float var = s2[16 + bc] * INV_M - m * m;
    float inv = rsqrtf(var + 1e-5f);
    float4 v = ((float4*)out)[i4];
    v.x = (v.x - m) * inv; v.y = (v.y - m) * inv;
    v.z = (v.z - m) * inv; v.w = (v.w - m) * inv;
    ((float4*)out)[i4] = v;
}

extern "C" void kernel_launch(void* const* d_in, const int* in_sizes, int n_in,
                              void* d_out, int out_size, void* d_ws, size_t ws_size,
                              hipStream_t stream) {
    const float* t  = (const float*)d_in[0];
    const int*   x  = (const int*)d_in[1];
    const int*   y  = (const int*)d_in[2];
    const int*   p  = (const int*)d_in[3];
    const int*   b  = (const int*)d_in[4];
    const float* conv1_w = (const float*)d_in[5];
    // d_in[6], d_in[7] (fc1_w, fc2_w): unused — attention is exactly uniform
    const float* dyn_w   = (const float*)d_in[8];
    const float* conv3_w = (const float*)d_in[9];
    float* out = (float*)d_out;
    int n = in_sizes[0];

    long availF = (long)(ws_size / sizeof(float));
    long need = (long)TOT + 2L * n + 8192;       // vox + rec + tail
    int useBuckets = (availF >= need);

    float* ws   = (float*)d_ws;
    float* vox  = ws;                                        // TOT
    int2*  rec  = (int2*)(ws + TOT);                         // n records
    float* tail = ws + TOT + (useBuckets ? 2L * n : 0);
    // zeroed region: gmax(8) s1(32) s2(32) hist(1152) = 1224
    unsigned* gmax    = (unsigned*)tail;                     // +0
    float*    s1      = tail + 8;                            // +8
    float*    s2      = tail + 40;                           // +40
    unsigned* hist    = (unsigned*)(tail + 72);              // +72  (1152)
    // non-zeroed:
    float*    Kc      = tail + 1224;                         // +1224 (12)
    int*      start   = (int*)(tail + 1236);                 // +1236 (12)
    unsigned* segbase = (unsigned*)(tail + 1248);            // +1248 (1152)
    unsigned* cursor  = (unsigned*)(tail + 2400);            // +2400 (1152)

    hipMemsetAsync(tail, 0, 1224 * sizeof(float), stream);

    k_bounds<<<1, 64, 0, stream>>>(b, start, n, conv1_w, dyn_w, conv3_w, Kc);
    k_tmax<<<512, 256, 0, stream>>>(t, start, gmax);
    if (useBuckets) {
        k_hist<<<512, 256, 0, stream>>>(t, y, gmax, start, hist);
        k_scan<<<1, 1024, 0, stream>>>(start, hist, segbase, cursor);
        k_place<<<2048, 256, 0, stream>>>(t, x, y, p, gmax, start, cursor, rec);
        k_scat_b<<<dim3(9, 8, NYG), 256, 0, stream>>>(rec, hist, segbase, vox);
    } else {
        k_scat<<<dim3(9, 8, 1), 1024, 0, stream>>>(t, x, y, p, gmax, start, vox);
    }
    k_mask<<<576, 256, 0, stream>>>(vox, out, s1);           // d_out holds mask
    k_g<<<1024, 256, 0, stream>>>(vox, out, s1, Kc, s2);
    k_norm<<<TOT / 1024, 256, 0, stream>>>(out, s2);
}